// Round 1
// baseline (1482.920 us; speedup 1.0000x reference)
//
#include <hip/hip_runtime.h>

#define N_NODES 50000
#define N_EDGES 1600000

typedef _Float16 h8 __attribute__((ext_vector_type(8)));
typedef float f4 __attribute__((ext_vector_type(4)));

__device__ inline h8 ld_h8(const _Float16* p) { return *(const h8*)p; }

__device__ inline h8 cvt2h8(f4 a, f4 b) {
    h8 r;
    r[0] = (_Float16)a[0]; r[1] = (_Float16)a[1]; r[2] = (_Float16)a[2]; r[3] = (_Float16)a[3];
    r[4] = (_Float16)b[0]; r[5] = (_Float16)b[1]; r[6] = (_Float16)b[2]; r[7] = (_Float16)b[3];
    return r;
}

// ---------------- prep kernels ----------------
// Wm1/Wm2 are emitted as the final LDS image for the msg kernel:
//   img[(ks*128 + o)*32 + (q ^ ((o>>1)&3))*8 + j] = W[(ks*32 + q*8 + j)*128 + o]
// XOR chunk swizzle -> uniform 2-way LDS bank access on ds_read_b128 (free).

__global__ void prep_weights(const float* __restrict__ Wm1, const float* __restrict__ Wa1,
                             const float* __restrict__ Wm2, const float* __restrict__ Wa2,
                             const float* __restrict__ W1,
                             _Float16* __restrict__ Wm1t, _Float16* __restrict__ Wa1t,
                             _Float16* __restrict__ Wm2t, _Float16* __restrict__ Wa2t,
                             _Float16* __restrict__ W1t)
{
    int i = blockIdx.x * 256 + threadIdx.x;
    if (i < 12288) {                       // Wm1: 128*96, msg-swizzled image
        int o = i / 96, k = i % 96;
        int ks = k >> 5, q = (k >> 3) & 3, j = k & 7;
        int c = q ^ ((o >> 1) & 3);
        Wm1t[(ks * 128 + o) * 32 + c * 8 + j] = (_Float16)Wm1[k * 128 + o];
    } else if (i < 36864) {                // + 128*192 (Wa1, unchanged layout)
        int jj = i - 12288; int o = jj / 192, k = jj % 192;
        Wa1t[o * 200 + k] = (_Float16)Wa1[k * 128 + o];
    } else if (i < 57344) {                // + 128*160 (Wm2, msg-swizzled image)
        int jj = i - 36864; int o = jj / 160, k = jj % 160;
        int ks = k >> 5, q = (k >> 3) & 3, j = k & 7;
        int c = q ^ ((o >> 1) & 3);
        Wm2t[(ks * 128 + o) * 32 + c * 8 + j] = (_Float16)Wm2[k * 128 + o];
    } else if (i < 90112) {                // + 128*256 (Wa2, unchanged)
        int jj = i - 57344; int o = jj >> 8, k = jj & 255;
        Wa2t[(o << 8) + k] = (_Float16)Wa2[k * 128 + o];
    } else if (i < 122880) {               // + 128*256 (W1, unchanged)
        int jj = i - 90112; int o = jj >> 8, k = jj & 255;
        W1t[(o << 8) + k] = (_Float16)W1[k * 128 + o];
    }
}

__global__ void cvt_nfeats(const float* __restrict__ nf, _Float16* __restrict__ nf16)
{
    int i = blockIdx.x * 256 + threadIdx.x;   // exactly N*64 = 3.2M threads
    nf16[i] = (_Float16)nf[i];
}

// ---------------- counting sort of edges by dst ----------------

__global__ void hist_kernel(const int* __restrict__ dst, int* __restrict__ cnt)
{
    int e = blockIdx.x * 256 + threadIdx.x;   // exactly E threads
    atomicAdd(cnt + dst[e], 1);
}

__global__ void scan1_kernel(const int* __restrict__ cnt, int* __restrict__ tmp,
                             int* __restrict__ bsum)
{
    __shared__ int sh[256];
    int t = threadIdx.x, i = blockIdx.x * 256 + t;
    int v = (i < N_NODES) ? cnt[i] : 0;
    sh[t] = v; __syncthreads();
    for (int off = 1; off < 256; off <<= 1) {
        int x = (t >= off) ? sh[t - off] : 0;
        __syncthreads();
        sh[t] += x;
        __syncthreads();
    }
    if (i < N_NODES) tmp[i] = sh[t];
    if (t == 255) bsum[blockIdx.x] = sh[255];
}

__global__ void scan2_kernel(const int* __restrict__ bsum, int* __restrict__ bbase)
{
    __shared__ int sh[256];
    int t = threadIdx.x;
    int v = (t < 196) ? bsum[t] : 0;
    sh[t] = v; __syncthreads();
    for (int off = 1; off < 256; off <<= 1) {
        int x = (t >= off) ? sh[t - off] : 0;
        __syncthreads();
        sh[t] += x;
        __syncthreads();
    }
    if (t < 196) bbase[t] = sh[t] - v;   // exclusive
}

__global__ void scan3_kernel(const int* __restrict__ cnt, const int* __restrict__ tmp,
                             const int* __restrict__ bbase, int* __restrict__ cursor)
{
    int t = threadIdx.x, b = blockIdx.x, i = b * 256 + t;
    if (i < N_NODES) cursor[i] = tmp[i] - cnt[i] + bbase[b];
}

// scatter now materializes, in dst-sorted slot order:
//   pairs[pos] = (edge_id, src_node)   -- one 8-B load in msg gets both
//   dsts[pos]  = dst_node              -- coalesced int4 loads for the reduce
__global__ void scatter_kernel(const int* __restrict__ src, const int* __restrict__ dst,
                               int* __restrict__ cursor,
                               int2* __restrict__ pairs, int* __restrict__ dsts)
{
    int e = blockIdx.x * 256 + threadIdx.x;   // exactly E threads
    int d = dst[e];
    int pos = atomicAdd(cursor + d, 1);
    pairs[pos] = make_int2(e, src[e]);
    dsts[pos] = d;
}

// ---------------- edge message kernel ----------------
// Block = 128 dst-sorted edge slots, 4 waves x 32 slots. LDS holds ONLY the
// swizzled B image ((K+32)*128 fp16): L1 24576 B -> 6-block LDS cap,
// L2 40960 B -> exactly 4 blocks/CU. Single barrier. Post-GEMM segmented
// reduce is done fully in registers: a wave-uniform check on the 16-row
// group's first/last dst takes a 2-shuffle fast path (~62% of groups);
// otherwise per-lane 4-row runs with boundary atomics.
template<int KSRC_H, int MINW>
__launch_bounds__(256, MINW)
__global__ void msg_kernel_sorted(const _Float16* __restrict__ ntab,
                                  const float* __restrict__ efeats,
                                  const int2* __restrict__ pairs,
                                  const int* __restrict__ dsts,
                                  const _Float16* __restrict__ Wt,
                                  const float* __restrict__ bias,
                                  float* __restrict__ sacc)
{
    constexpr int EFSTEP = KSRC_H / 32;
    constexpr int KSTEPS = EFSTEP + 1;
    constexpr int BH = (KSRC_H + 32) * 128;          // fp16 elems
    __shared__ __align__(16) _Float16 Bsh[BH];

    const int tid = threadIdx.x;
    const int wave = tid >> 6, lane = tid & 63;
    const int q = lane >> 4, l15 = lane & 15;
    const int wbase = blockIdx.x * 128 + wave * 32;

    // ---- early-issued gathers: overlap with B staging below ----
    const int2 p0 = pairs[wbase + l15];
    const int2 p1 = pairs[wbase + 16 + l15];
    const _Float16* r0 = ntab + (size_t)p0.y * KSRC_H + q * 8;
    const _Float16* r1 = ntab + (size_t)p1.y * KSRC_H + q * 8;
    h8 a0p = ld_h8(r0);
    h8 a1p = ld_h8(r1);
    const float* ep0 = efeats + (size_t)p0.x * 32 + q * 8;
    const float* ep1 = efeats + (size_t)p1.x * 32 + q * 8;
    f4 e0a, e0b, e1a, e1b;
    if constexpr (KSRC_H > 64) {       // L2 has VGPR headroom (MINW=4): prefetch efeats too
        e0a = *(const f4*)ep0; e0b = *(const f4*)(ep0 + 4);
        e1a = *(const f4*)ep1; e1b = *(const f4*)(ep1 + 4);
    }

    // ---- stage B (linear copy; image pre-swizzled on host side) ----
    {
        const uint4* s4 = (const uint4*)Wt;
        uint4* d4 = (uint4*)Bsh;
        constexpr int n4 = BH / 8;
        for (int i = tid; i < n4; i += 256) d4[i] = s4[i];
    }
    __syncthreads();

    f4 acc[2][8];
#pragma unroll
    for (int t = 0; t < 2; t++)
#pragma unroll
        for (int nt = 0; nt < 8; nt++) acc[t][nt] = (f4){0.f, 0.f, 0.f, 0.f};

    const _Float16* bp = Bsh + l15 * 32 + ((q ^ ((l15 >> 1) & 3)) << 3);
#pragma unroll
    for (int ks = 0; ks < KSTEPS; ks++) {
        h8 a0, a1;
        if (ks == 0) {
            a0 = a0p; a1 = a1p;
        } else if (ks < EFSTEP) {
            a0 = ld_h8(r0 + ks * 32);
            a1 = ld_h8(r1 + ks * 32);
        } else {
            if constexpr (KSRC_H > 64) {
                a0 = cvt2h8(e0a, e0b);
                a1 = cvt2h8(e1a, e1b);
            } else {
                a0 = cvt2h8(*(const f4*)ep0, *(const f4*)(ep0 + 4));
                a1 = cvt2h8(*(const f4*)ep1, *(const f4*)(ep1 + 4));
            }
        }
#pragma unroll
        for (int nt = 0; nt < 8; nt++) {
            h8 b = ld_h8(bp + ks * 4096 + nt * 512);
            acc[0][nt] = __builtin_amdgcn_mfma_f32_16x16x32_f16(a0, b, acc[0][nt], 0, 0, 0);
            acc[1][nt] = __builtin_amdgcn_mfma_f32_16x16x32_f16(a1, b, acc[1][nt], 0, 0, 0);
        }
    }

    // ---- in-register segmented reduce (no barriers, no LDS) ----
    float bv[8];
#pragma unroll
    for (int nt = 0; nt < 8; nt++) bv[nt] = bias[nt * 16 + l15];

#pragma unroll
    for (int t = 0; t < 2; t++) {
        const int rbase = wbase + t * 16;
        const int4 dv = *(const int4*)(dsts + rbase + q * 4);   // dsts of my 4 rows
        const int dfirst = __shfl(dv.x, l15, 64);               // d of row rbase
        const int dlast  = __shfl(dv.w, 48 + l15, 64);          // d of row rbase+15
        if (dfirst == dlast) {
            // uniform 16-row group: full column sum, one atomic per col
#pragma unroll
            for (int nt = 0; nt < 8; nt++) {
                float sv = fmaxf(acc[t][nt][0] + bv[nt], 0.f)
                         + fmaxf(acc[t][nt][1] + bv[nt], 0.f)
                         + fmaxf(acc[t][nt][2] + bv[nt], 0.f)
                         + fmaxf(acc[t][nt][3] + bv[nt], 0.f);
                sv += __shfl_xor(sv, 16, 64);
                sv += __shfl_xor(sv, 32, 64);
                if (q == (nt >> 1))
                    atomicAdd(sacc + (size_t)dfirst * 128 + nt * 16 + l15, sv);
            }
        } else {
            // mixed group: per-lane runs over its 4 rows
            float a[8];
#pragma unroll
            for (int nt = 0; nt < 8; nt++) a[nt] = fmaxf(acc[t][nt][0] + bv[nt], 0.f);
            int dp = dv.x;
#pragma unroll
            for (int r = 1; r < 4; r++) {
                const int dr = (r == 1) ? dv.y : (r == 2) ? dv.z : dv.w;
                if (dr != dp) {
#pragma unroll
                    for (int nt = 0; nt < 8; nt++) {
                        atomicAdd(sacc + (size_t)dp * 128 + nt * 16 + l15, a[nt]);
                        a[nt] = fmaxf(acc[t][nt][r] + bv[nt], 0.f);
                    }
                    dp = dr;
                } else {
#pragma unroll
                    for (int nt = 0; nt < 8; nt++) a[nt] += fmaxf(acc[t][nt][r] + bv[nt], 0.f);
                }
            }
#pragma unroll
            for (int nt = 0; nt < 8; nt++)
                atomicAdd(sacc + (size_t)dp * 128 + nt * 16 + l15, a[nt]);
        }
    }
}

// ---------------- node apply kernel (unchanged) ----------------
template<int KSRC_H, bool SWIZ, int KPAD>
__launch_bounds__(256)
__global__ void apply_kernel(const _Float16* __restrict__ ntab,
                             const float* __restrict__ sacc,
                             const int* __restrict__ cnt,
                             const _Float16* __restrict__ Wt,
                             const float* __restrict__ bias,
                             _Float16* __restrict__ outtab)
{
    constexpr int KSTEPS = (KSRC_H + 128) / 32;
    __shared__ __align__(16) _Float16 Bsh[128 * KPAD];

    const int tid = threadIdx.x;
    if (SWIZ) {
        const uint4* s4 = (const uint4*)Wt;
        uint4* d4 = (uint4*)Bsh;
        for (int i = tid; i < 4096; i += 256) {
            int n = i >> 5, c = i & 31;
            d4[(n << 5) | (c ^ (n & 31))] = s4[i];
        }
    } else {
        const uint4* s4 = (const uint4*)Wt;
        uint4* d4 = (uint4*)Bsh;
        constexpr int n4 = 128 * KPAD / 8;
        for (int i = tid; i < n4; i += 256) d4[i] = s4[i];
    }
    __syncthreads();

    const int wave = tid >> 6, lane = tid & 63;
    const int q = lane >> 4, l15 = lane & 15;
    const int nbase = blockIdx.x * 128 + wave * 32;

    const int n0 = nbase + l15, n1 = nbase + 16 + l15;
    const int n0c = min(n0, N_NODES - 1), n1c = min(n1, N_NODES - 1);
    const _Float16* r0 = ntab + (size_t)n0c * KSRC_H;
    const _Float16* r1 = ntab + (size_t)n1c * KSRC_H;
    const float rcp0 = 1.0f / fmaxf((float)cnt[n0c], 1.0f);
    const float rcp1 = 1.0f / fmaxf((float)cnt[n1c], 1.0f);

    f4 acc[2][8];
#pragma unroll
    for (int t = 0; t < 2; t++)
#pragma unroll
        for (int nt = 0; nt < 8; nt++) acc[t][nt] = (f4){0.f, 0.f, 0.f, 0.f};

#pragma unroll
    for (int ks = 0; ks < KSTEPS; ks++) {
        h8 a0, a1;
        if (ks < KSRC_H / 32) {
            a0 = ld_h8(r0 + ks * 32 + q * 8);
            a1 = ld_h8(r1 + ks * 32 + q * 8);
        } else {
            const int kk = ks * 32 - KSRC_H + q * 8;
            const float* p0 = sacc + (size_t)n0c * 128 + kk;
            const float* p1 = sacc + (size_t)n1c * 128 + kk;
            f4 u0 = *(const f4*)p0 * rcp0, v0 = *(const f4*)(p0 + 4) * rcp0;
            f4 u1 = *(const f4*)p1 * rcp1, v1 = *(const f4*)(p1 + 4) * rcp1;
            a0 = cvt2h8(u0, v0);
            a1 = cvt2h8(u1, v1);
        }
#pragma unroll
        for (int nt = 0; nt < 8; nt++) {
            h8 b;
            if (SWIZ) {
                const int nrow = nt * 16 + l15;
                const int chunk = ((ks << 2) | q) ^ (nrow & 31);
                b = ld_h8(Bsh + (((nrow << 5) | chunk) << 3));
            } else {
                b = ld_h8(&Bsh[(nt * 16 + l15) * KPAD + ks * 32 + q * 8]);
            }
            acc[0][nt] = __builtin_amdgcn_mfma_f32_16x16x32_f16(a0, b, acc[0][nt], 0, 0, 0);
            acc[1][nt] = __builtin_amdgcn_mfma_f32_16x16x32_f16(a1, b, acc[1][nt], 0, 0, 0);
        }
    }

#pragma unroll
    for (int nt = 0; nt < 8; nt++) {
        const int col = nt * 16 + l15;
        const float bv = bias[col];
#pragma unroll
        for (int t = 0; t < 2; t++)
#pragma unroll
            for (int r = 0; r < 4; r++) {
                const int node = nbase + t * 16 + q * 4 + r;
                if (node < N_NODES) {
                    float v = fmaxf(acc[t][nt][r] + bv, 0.f);
                    outtab[(size_t)node * 128 + col] = (_Float16)v;
                }
            }
    }
}

// ---------------- edge predictor kernel (unchanged) ----------------
__launch_bounds__(256)
__global__ void pred_kernel(const _Float16* __restrict__ h2,
                            const int* __restrict__ src,
                            const int* __restrict__ dst,
                            const _Float16* __restrict__ W1t,  // [128][256] unpadded
                            const float* __restrict__ b1,
                            const float* __restrict__ W2,      // [128][2] fp32
                            const float* __restrict__ b2,
                            float* __restrict__ out)
{
    __shared__ __align__(16) _Float16 Bsh[128 * 256];

    const int tid = threadIdx.x;
    {
        const uint4* s4 = (const uint4*)W1t;
        uint4* d4 = (uint4*)Bsh;
        for (int i = tid; i < 4096; i += 256) {
            int n = i >> 5, c = i & 31;
            d4[(n << 5) | (c ^ (n & 31))] = s4[i];
        }
    }
    __syncthreads();

    const int wave = tid >> 6, lane = tid & 63;
    const int q = lane >> 4, l15 = lane & 15;
    const int ebase = blockIdx.x * 128 + wave * 32;

    const int e0 = ebase + l15, e1 = ebase + 16 + l15;
    const _Float16* rs0 = h2 + (size_t)src[e0] * 128;
    const _Float16* rd0 = h2 + (size_t)dst[e0] * 128;
    const _Float16* rs1 = h2 + (size_t)src[e1] * 128;
    const _Float16* rd1 = h2 + (size_t)dst[e1] * 128;

    f4 acc[2][8];
#pragma unroll
    for (int t = 0; t < 2; t++)
#pragma unroll
        for (int nt = 0; nt < 8; nt++) acc[t][nt] = (f4){0.f, 0.f, 0.f, 0.f};

#pragma unroll
    for (int ks = 0; ks < 8; ks++) {
        h8 a0, a1;
        if (ks < 4) {
            a0 = ld_h8(rs0 + ks * 32 + q * 8);
            a1 = ld_h8(rs1 + ks * 32 + q * 8);
        } else {
            a0 = ld_h8(rd0 + (ks - 4) * 32 + q * 8);
            a1 = ld_h8(rd1 + (ks - 4) * 32 + q * 8);
        }
#pragma unroll
        for (int nt = 0; nt < 8; nt++) {
            const int nrow = nt * 16 + l15;
            const int chunk = ((ks << 2) | q) ^ (nrow & 31);
            h8 b = ld_h8(Bsh + (((nrow << 5) | chunk) << 3));
            acc[0][nt] = __builtin_amdgcn_mfma_f32_16x16x32_f16(a0, b, acc[0][nt], 0, 0, 0);
            acc[1][nt] = __builtin_amdgcn_mfma_f32_16x16x32_f16(a1, b, acc[1][nt], 0, 0, 0);
        }
    }

    float o[2][4][2];
#pragma unroll
    for (int t = 0; t < 2; t++)
#pragma unroll
        for (int r = 0; r < 4; r++) { o[t][r][0] = 0.f; o[t][r][1] = 0.f; }

#pragma unroll
    for (int nt = 0; nt < 8; nt++) {
        const int nrow = nt * 16 + l15;
        const float bv = b1[nrow];
        const float w20 = W2[nrow * 2 + 0];
        const float w21 = W2[nrow * 2 + 1];
#pragma unroll
        for (int t = 0; t < 2; t++)
#pragma unroll
            for (int r = 0; r < 4; r++) {
                float y = fmaxf(acc[t][nt][r] + bv, 0.f);
                o[t][r][0] += y * w20;
                o[t][r][1] += y * w21;
            }
    }

#pragma unroll
    for (int m = 1; m < 16; m <<= 1) {
#pragma unroll
        for (int t = 0; t < 2; t++)
#pragma unroll
            for (int r = 0; r < 4; r++) {
                o[t][r][0] += __shfl_xor(o[t][r][0], m, 64);
                o[t][r][1] += __shfl_xor(o[t][r][1], m, 64);
            }
    }

    if (l15 < 8) {
        const int r = l15 >> 1, c = l15 & 1;
        const float bb = c ? b2[1] : b2[0];
#pragma unroll
        for (int t = 0; t < 2; t++) {
            float v0 = (r == 0) ? o[t][0][0] : (r == 1) ? o[t][1][0] : (r == 2) ? o[t][2][0] : o[t][3][0];
            float v1 = (r == 0) ? o[t][0][1] : (r == 1) ? o[t][1][1] : (r == 2) ? o[t][2][1] : o[t][3][1];
            float v = (c ? v1 : v0) + bb;
            out[(size_t)(ebase + t * 16 + q * 4 + r) * 2 + c] = v;
        }
    }
}

// ---------------- launch ----------------

extern "C" void kernel_launch(void* const* d_in, const int* in_sizes, int n_in,
                              void* d_out, int out_size, void* d_ws, size_t ws_size,
                              hipStream_t stream)
{
    const float* nfeats = (const float*)d_in[0];
    const float* efeats = (const float*)d_in[1];
    const int*   src    = (const int*)d_in[2];
    const int*   dst    = (const int*)d_in[3];
    const float* Wm1 = (const float*)d_in[4],  *bm1 = (const float*)d_in[5];
    const float* Wa1 = (const float*)d_in[6],  *ba1 = (const float*)d_in[7];
    const float* Wm2 = (const float*)d_in[8],  *bm2 = (const float*)d_in[9];
    const float* Wa2 = (const float*)d_in[10], *ba2 = (const float*)d_in[11];
    const float* W1  = (const float*)d_in[12], *b1  = (const float*)d_in[13];
    const float* W2  = (const float*)d_in[14], *b2  = (const float*)d_in[15];
    float* out = (float*)d_out;

    char* ws = (char*)d_ws;
    float*     s     = (float*)(ws);                   // 25,600,000 B
    int*       cnt   = (int*)(ws + 25600000);          //    200,000 B
    int*       tmp   = (int*)(ws + 25800000);          //    200,000 B
    int*       cursor= (int*)(ws + 26000000);          //    200,000 B
    int*       bsum  = (int*)(ws + 26200000);          //      1,024 B
    int*       bbase = (int*)(ws + 26201024);          //      1,024 B
    _Float16*  nf16  = (_Float16*)(ws + 26202048);     //  6,400,000 B
    int2*      pairs = (int2*)(ws + 32602048);         // 12,800,000 B (edge_id, src) per sorted slot
    int*       dsts  = (int*)(ws + 45402048);          //  6,400,000 B dst per sorted slot
    _Float16*  h1    = (_Float16*)(ws + 51802048);     // 12,800,000 B
    _Float16*  h2    = (_Float16*)(ws + 26202048);     // 12,800,000 B (aliases nf16 + pairs head; both dead by apply2)
    _Float16*  Wm1t  = (_Float16*)(ws + 64602048);     //     24,576 B (msg image, K=96)
    _Float16*  Wa1t  = (_Float16*)(ws + 64626624);     //     51,200 B
    _Float16*  Wm2t  = (_Float16*)(ws + 64677824);     //     40,960 B (msg image, K=160)
    _Float16*  Wa2t  = (_Float16*)(ws + 64718784);     //     65,536 B
    _Float16*  W1t   = (_Float16*)(ws + 64784320);     //     65,536 B  -> end 64,849,856

    hipMemsetAsync(s, 0, 25600000, stream);
    hipMemsetAsync(cnt, 0, 200000, stream);

    prep_weights<<<480, 256, 0, stream>>>(Wm1, Wa1, Wm2, Wa2, W1, Wm1t, Wa1t, Wm2t, Wa2t, W1t);
    cvt_nfeats<<<12500, 256, 0, stream>>>(nfeats, nf16);

    // counting sort of edges by dst
    hist_kernel<<<6250, 256, 0, stream>>>(dst, cnt);
    scan1_kernel<<<196, 256, 0, stream>>>(cnt, tmp, bsum);
    scan2_kernel<<<1, 256, 0, stream>>>(bsum, bbase);
    scan3_kernel<<<196, 256, 0, stream>>>(cnt, tmp, bbase, cursor);
    scatter_kernel<<<6250, 256, 0, stream>>>(src, dst, cursor, pairs, dsts);

    // layer 1 (LDS 24576 B; VGPR roof 102 via MINW=5 -> 20 waves/CU)
    msg_kernel_sorted<64, 5><<<12500, 256, 0, stream>>>(nf16, efeats, pairs, dsts, Wm1t, bm1, s);
    apply_kernel<64, false, 200><<<391, 256, 0, stream>>>(nf16, s, cnt, Wa1t, ba1, h1);

    // layer 2 (LDS 40960 B = exactly 4 blocks/CU; VGPR roof 128 via MINW=4)
    hipMemsetAsync(s, 0, 25600000, stream);
    msg_kernel_sorted<128, 4><<<12500, 256, 0, stream>>>(h1, efeats, pairs, dsts, Wm2t, bm2, s);
    apply_kernel<128, true, 256><<<391, 256, 0, stream>>>(h1, s, cnt, Wa2t, ba2, h2);

    // predictor
    pred_kernel<<<12500, 256, 0, stream>>>(h2, src, dst, W1t, b1, W2, b2, out);
}

// Round 2
// 1104.935 us; speedup vs baseline: 1.3421x; 1.3421x over previous
//
#include <hip/hip_runtime.h>

#define N_NODES 50000
#define N_EDGES 1600000

typedef _Float16 h8 __attribute__((ext_vector_type(8)));
typedef float f4 __attribute__((ext_vector_type(4)));

__device__ inline h8 ld_h8(const _Float16* p) { return *(const h8*)p; }

__device__ inline h8 cvt2h8(f4 a, f4 b) {
    h8 r;
    r[0] = (_Float16)a[0]; r[1] = (_Float16)a[1]; r[2] = (_Float16)a[2]; r[3] = (_Float16)a[3];
    r[4] = (_Float16)b[0]; r[5] = (_Float16)b[1]; r[6] = (_Float16)b[2]; r[7] = (_Float16)b[3];
    return r;
}

// ---------------- prep kernels ----------------
// Wm1/Wm2 are emitted as the final LDS image for the msg kernel:
//   img[(ks*128 + o)*32 + (q ^ ((o>>1)&3))*8 + j] = W[(ks*32 + q*8 + j)*128 + o]
// XOR chunk swizzle -> uniform 2-way LDS bank access on ds_read_b128 (free).

__global__ void prep_weights(const float* __restrict__ Wm1, const float* __restrict__ Wa1,
                             const float* __restrict__ Wm2, const float* __restrict__ Wa2,
                             const float* __restrict__ W1,
                             _Float16* __restrict__ Wm1t, _Float16* __restrict__ Wa1t,
                             _Float16* __restrict__ Wm2t, _Float16* __restrict__ Wa2t,
                             _Float16* __restrict__ W1t)
{
    int i = blockIdx.x * 256 + threadIdx.x;
    if (i < 12288) {                       // Wm1: 128*96, msg-swizzled image
        int o = i / 96, k = i % 96;
        int ks = k >> 5, q = (k >> 3) & 3, j = k & 7;
        int c = q ^ ((o >> 1) & 3);
        Wm1t[(ks * 128 + o) * 32 + c * 8 + j] = (_Float16)Wm1[k * 128 + o];
    } else if (i < 36864) {                // + 128*192 (Wa1, unchanged layout)
        int jj = i - 12288; int o = jj / 192, k = jj % 192;
        Wa1t[o * 200 + k] = (_Float16)Wa1[k * 128 + o];
    } else if (i < 57344) {                // + 128*160 (Wm2, msg-swizzled image)
        int jj = i - 36864; int o = jj / 160, k = jj % 160;
        int ks = k >> 5, q = (k >> 3) & 3, j = k & 7;
        int c = q ^ ((o >> 1) & 3);
        Wm2t[(ks * 128 + o) * 32 + c * 8 + j] = (_Float16)Wm2[k * 128 + o];
    } else if (i < 90112) {                // + 128*256 (Wa2, unchanged)
        int jj = i - 57344; int o = jj >> 8, k = jj & 255;
        Wa2t[(o << 8) + k] = (_Float16)Wa2[k * 128 + o];
    } else if (i < 122880) {               // + 128*256 (W1, unchanged)
        int jj = i - 90112; int o = jj >> 8, k = jj & 255;
        W1t[(o << 8) + k] = (_Float16)W1[k * 128 + o];
    }
}

__global__ void cvt_nfeats(const float* __restrict__ nf, _Float16* __restrict__ nf16)
{
    int i = blockIdx.x * 256 + threadIdx.x;   // exactly N*64 = 3.2M threads
    nf16[i] = (_Float16)nf[i];
}

// ---------------- counting sort of edges by dst ----------------

__global__ void hist_kernel(const int* __restrict__ dst, int* __restrict__ cnt)
{
    int e = blockIdx.x * 256 + threadIdx.x;   // exactly E threads
    atomicAdd(cnt + dst[e], 1);
}

__global__ void scan1_kernel(const int* __restrict__ cnt, int* __restrict__ tmp,
                             int* __restrict__ bsum)
{
    __shared__ int sh[256];
    int t = threadIdx.x, i = blockIdx.x * 256 + t;
    int v = (i < N_NODES) ? cnt[i] : 0;
    sh[t] = v; __syncthreads();
    for (int off = 1; off < 256; off <<= 1) {
        int x = (t >= off) ? sh[t - off] : 0;
        __syncthreads();
        sh[t] += x;
        __syncthreads();
    }
    if (i < N_NODES) tmp[i] = sh[t];
    if (t == 255) bsum[blockIdx.x] = sh[255];
}

__global__ void scan2_kernel(const int* __restrict__ bsum, int* __restrict__ bbase)
{
    __shared__ int sh[256];
    int t = threadIdx.x;
    int v = (t < 196) ? bsum[t] : 0;
    sh[t] = v; __syncthreads();
    for (int off = 1; off < 256; off <<= 1) {
        int x = (t >= off) ? sh[t - off] : 0;
        __syncthreads();
        sh[t] += x;
        __syncthreads();
    }
    if (t < 196) bbase[t] = sh[t] - v;   // exclusive
}

__global__ void scan3_kernel(const int* __restrict__ cnt, const int* __restrict__ tmp,
                             const int* __restrict__ bbase, int* __restrict__ cursor)
{
    int t = threadIdx.x, b = blockIdx.x, i = b * 256 + t;
    if (i < N_NODES) cursor[i] = tmp[i] - cnt[i] + bbase[b];
}

// scatter materializes, in dst-sorted slot order:
//   pairs[pos] = (edge_id, src_node)   -- one 8-B load in msg gets both
//   dsts[pos]  = dst_node              -- coalesced int4 loads for the reduce
__global__ void scatter_kernel(const int* __restrict__ src, const int* __restrict__ dst,
                               int* __restrict__ cursor,
                               int2* __restrict__ pairs, int* __restrict__ dsts)
{
    int e = blockIdx.x * 256 + threadIdx.x;   // exactly E threads
    int d = dst[e];
    int pos = atomicAdd(cursor + d, 1);
    pairs[pos] = make_int2(e, src[e]);
    dsts[pos] = d;
}

// ---------------- edge message kernel ----------------
// Block = 128 dst-sorted edge slots, 4 waves x 32 slots. LDS holds the swizzled
// B image during the GEMM; after one barrier it is reused as per-wave scratch
// for the rare mixed-dst reduce path. Segmented reduce hierarchy (dsts sorted,
// so first==last implies uniform):
//   32-row uniform (p~38%): 2 dense 64-lane atomics per wave
//   16-row uniform:         2 dense 64-lane atomics per group
//   mixed 16-row  (p~38%):  spill to wave-private LDS scratch, column-serial
//                           run-length scan with WAVE-UNIFORM branches ->
//                           every boundary emits 2 dense 64-lane atomics.
template<int KSRC_H, int MINW>
__launch_bounds__(256, MINW)
__global__ void msg_kernel_sorted(const _Float16* __restrict__ ntab,
                                  const float* __restrict__ efeats,
                                  const int2* __restrict__ pairs,
                                  const int* __restrict__ dsts,
                                  const _Float16* __restrict__ Wt,
                                  const float* __restrict__ bias,
                                  float* __restrict__ sacc)
{
    constexpr int EFSTEP = KSRC_H / 32;
    constexpr int KSTEPS = EFSTEP + 1;
    constexpr int BH = (KSRC_H + 32) * 128;              // fp16 elems
    constexpr int BBYTES = BH * 2;
    constexpr int SCRBYTES = 4 * 16 * 132 * 4;           // 33792
    constexpr int LDSBYTES = BBYTES > SCRBYTES ? BBYTES : SCRBYTES;
    __shared__ __align__(16) char smem[LDSBYTES];
    _Float16* Bsh = (_Float16*)smem;

    const int tid = threadIdx.x;
    const int wave = tid >> 6, lane = tid & 63;
    const int q = lane >> 4, l15 = lane & 15;
    const int wbase = blockIdx.x * 128 + wave * 32;

    // ---- early-issued gathers: overlap with B staging below ----
    const int2 p0 = pairs[wbase + l15];
    const int2 p1 = pairs[wbase + 16 + l15];
    const _Float16* r0 = ntab + (size_t)p0.y * KSRC_H + q * 8;
    const _Float16* r1 = ntab + (size_t)p1.y * KSRC_H + q * 8;
    h8 a0p = ld_h8(r0);
    h8 a1p = ld_h8(r1);
    const float* ep0 = efeats + (size_t)p0.x * 32 + q * 8;
    const float* ep1 = efeats + (size_t)p1.x * 32 + q * 8;
    f4 e0a, e0b, e1a, e1b;
    if constexpr (KSRC_H > 64) {       // L2 has VGPR headroom: prefetch efeats too
        e0a = *(const f4*)ep0; e0b = *(const f4*)(ep0 + 4);
        e1a = *(const f4*)ep1; e1b = *(const f4*)(ep1 + 4);
    }

    // ---- stage B (linear copy; image pre-swizzled on host side) ----
    {
        const uint4* s4 = (const uint4*)Wt;
        uint4* d4 = (uint4*)smem;
        constexpr int n4 = BH / 8;
        for (int i = tid; i < n4; i += 256) d4[i] = s4[i];
    }
    __syncthreads();

    f4 acc[2][8];
#pragma unroll
    for (int t = 0; t < 2; t++)
#pragma unroll
        for (int nt = 0; nt < 8; nt++) acc[t][nt] = (f4){0.f, 0.f, 0.f, 0.f};

    const _Float16* bp = Bsh + l15 * 32 + ((q ^ ((l15 >> 1) & 3)) << 3);
#pragma unroll
    for (int ks = 0; ks < KSTEPS; ks++) {
        h8 a0, a1;
        if (ks == 0) {
            a0 = a0p; a1 = a1p;
        } else if (ks < EFSTEP) {
            a0 = ld_h8(r0 + ks * 32);
            a1 = ld_h8(r1 + ks * 32);
        } else {
            if constexpr (KSRC_H > 64) {
                a0 = cvt2h8(e0a, e0b);
                a1 = cvt2h8(e1a, e1b);
            } else {
                a0 = cvt2h8(*(const f4*)ep0, *(const f4*)(ep0 + 4));
                a1 = cvt2h8(*(const f4*)ep1, *(const f4*)(ep1 + 4));
            }
        }
#pragma unroll
        for (int nt = 0; nt < 8; nt++) {
            h8 b = ld_h8(bp + ks * 4096 + nt * 512);
            acc[0][nt] = __builtin_amdgcn_mfma_f32_16x16x32_f16(a0, b, acc[0][nt], 0, 0, 0);
            acc[1][nt] = __builtin_amdgcn_mfma_f32_16x16x32_f16(a1, b, acc[1][nt], 0, 0, 0);
        }
    }

    __syncthreads();   // B image dead everywhere; smem becomes per-wave scratch

    // ---- segmented reduce ----
    float* wsch = (float*)smem + wave * 2112;   // 16*132 floats per wave

    float bv[8];
#pragma unroll
    for (int nt = 0; nt < 8; nt++) bv[nt] = bias[nt * 16 + l15];

    const int4 dv0 = *(const int4*)(dsts + wbase + q * 4);
    const int4 dv1 = *(const int4*)(dsts + wbase + 16 + q * 4);
    const int df0 = __shfl(dv0.x, l15, 64);        // dst of row wbase+0
    const int dl0 = __shfl(dv0.w, 48 + l15, 64);   // dst of row wbase+15
    const int df1 = __shfl(dv1.x, l15, 64);        // dst of row wbase+16
    const int dl1 = __shfl(dv1.w, 48 + l15, 64);   // dst of row wbase+31

    auto reduce16 = [&](const f4 (&a)[8], int df, int dl, int rbase) {
        if (df == dl) {
            float sv[8];
#pragma unroll
            for (int nt = 0; nt < 8; nt++) {
                float s = fmaxf(a[nt][0] + bv[nt], 0.f) + fmaxf(a[nt][1] + bv[nt], 0.f)
                        + fmaxf(a[nt][2] + bv[nt], 0.f) + fmaxf(a[nt][3] + bv[nt], 0.f);
                s += __shfl_xor(s, 16, 64);
                s += __shfl_xor(s, 32, 64);
                sv[nt] = s;
            }
#pragma unroll
            for (int i = 0; i < 2; i++) {
                float x = (q == 0) ? sv[i*4] : (q == 1) ? sv[i*4+1] : (q == 2) ? sv[i*4+2] : sv[i*4+3];
                atomicAdd(sacc + (size_t)df * 128 + i * 64 + lane, x);
            }
        } else {
            // mixed group: spill to wave scratch, column-serial uniform scan
#pragma unroll
            for (int nt = 0; nt < 8; nt++)
#pragma unroll
                for (int r = 0; r < 4; r++)
                    wsch[(q * 4 + r) * 132 + nt * 16 + l15] = fmaxf(a[nt][r] + bv[nt], 0.f);
            const int rb = __builtin_amdgcn_readfirstlane(rbase);
            float s0 = 0.f, s1 = 0.f;
            int dp = dsts[rb];
            for (int rr = 0; rr < 16; rr++) {
                const int d = dsts[rb + rr];          // wave-uniform scalar load
                const float v0 = wsch[rr * 132 + lane];
                const float v1 = wsch[rr * 132 + 64 + lane];
                if (d != dp) {                         // wave-uniform branch
                    atomicAdd(sacc + (size_t)dp * 128 + lane, s0);
                    atomicAdd(sacc + (size_t)dp * 128 + 64 + lane, s1);
                    s0 = v0; s1 = v1; dp = d;
                } else {
                    s0 += v0; s1 += v1;
                }
            }
            atomicAdd(sacc + (size_t)dp * 128 + lane, s0);
            atomicAdd(sacc + (size_t)dp * 128 + 64 + lane, s1);
        }
    };

    if (df0 == dl1) {
        // whole 32-row wave segment is one dst (sorted -> uniform)
        float sv[8];
#pragma unroll
        for (int nt = 0; nt < 8; nt++) {
            float s = fmaxf(acc[0][nt][0] + bv[nt], 0.f) + fmaxf(acc[0][nt][1] + bv[nt], 0.f)
                    + fmaxf(acc[0][nt][2] + bv[nt], 0.f) + fmaxf(acc[0][nt][3] + bv[nt], 0.f)
                    + fmaxf(acc[1][nt][0] + bv[nt], 0.f) + fmaxf(acc[1][nt][1] + bv[nt], 0.f)
                    + fmaxf(acc[1][nt][2] + bv[nt], 0.f) + fmaxf(acc[1][nt][3] + bv[nt], 0.f);
            s += __shfl_xor(s, 16, 64);
            s += __shfl_xor(s, 32, 64);
            sv[nt] = s;
        }
#pragma unroll
        for (int i = 0; i < 2; i++) {
            float x = (q == 0) ? sv[i*4] : (q == 1) ? sv[i*4+1] : (q == 2) ? sv[i*4+2] : sv[i*4+3];
            atomicAdd(sacc + (size_t)df0 * 128 + i * 64 + lane, x);
        }
    } else {
        reduce16(acc[0], df0, dl0, wbase);
        reduce16(acc[1], df1, dl1, wbase + 16);
    }
}

// ---------------- node apply kernel (unchanged) ----------------
template<int KSRC_H, bool SWIZ, int KPAD>
__launch_bounds__(256)
__global__ void apply_kernel(const _Float16* __restrict__ ntab,
                             const float* __restrict__ sacc,
                             const int* __restrict__ cnt,
                             const _Float16* __restrict__ Wt,
                             const float* __restrict__ bias,
                             _Float16* __restrict__ outtab)
{
    constexpr int KSTEPS = (KSRC_H + 128) / 32;
    __shared__ __align__(16) _Float16 Bsh[128 * KPAD];

    const int tid = threadIdx.x;
    if (SWIZ) {
        const uint4* s4 = (const uint4*)Wt;
        uint4* d4 = (uint4*)Bsh;
        for (int i = tid; i < 4096; i += 256) {
            int n = i >> 5, c = i & 31;
            d4[(n << 5) | (c ^ (n & 31))] = s4[i];
        }
    } else {
        const uint4* s4 = (const uint4*)Wt;
        uint4* d4 = (uint4*)Bsh;
        constexpr int n4 = 128 * KPAD / 8;
        for (int i = tid; i < n4; i += 256) d4[i] = s4[i];
    }
    __syncthreads();

    const int wave = tid >> 6, lane = tid & 63;
    const int q = lane >> 4, l15 = lane & 15;
    const int nbase = blockIdx.x * 128 + wave * 32;

    const int n0 = nbase + l15, n1 = nbase + 16 + l15;
    const int n0c = min(n0, N_NODES - 1), n1c = min(n1, N_NODES - 1);
    const _Float16* r0 = ntab + (size_t)n0c * KSRC_H;
    const _Float16* r1 = ntab + (size_t)n1c * KSRC_H;
    const float rcp0 = 1.0f / fmaxf((float)cnt[n0c], 1.0f);
    const float rcp1 = 1.0f / fmaxf((float)cnt[n1c], 1.0f);

    f4 acc[2][8];
#pragma unroll
    for (int t = 0; t < 2; t++)
#pragma unroll
        for (int nt = 0; nt < 8; nt++) acc[t][nt] = (f4){0.f, 0.f, 0.f, 0.f};

#pragma unroll
    for (int ks = 0; ks < KSTEPS; ks++) {
        h8 a0, a1;
        if (ks < KSRC_H / 32) {
            a0 = ld_h8(r0 + ks * 32 + q * 8);
            a1 = ld_h8(r1 + ks * 32 + q * 8);
        } else {
            const int kk = ks * 32 - KSRC_H + q * 8;
            const float* p0 = sacc + (size_t)n0c * 128 + kk;
            const float* p1 = sacc + (size_t)n1c * 128 + kk;
            f4 u0 = *(const f4*)p0 * rcp0, v0 = *(const f4*)(p0 + 4) * rcp0;
            f4 u1 = *(const f4*)p1 * rcp1, v1 = *(const f4*)(p1 + 4) * rcp1;
            a0 = cvt2h8(u0, v0);
            a1 = cvt2h8(u1, v1);
        }
#pragma unroll
        for (int nt = 0; nt < 8; nt++) {
            h8 b;
            if (SWIZ) {
                const int nrow = nt * 16 + l15;
                const int chunk = ((ks << 2) | q) ^ (nrow & 31);
                b = ld_h8(Bsh + (((nrow << 5) | chunk) << 3));
            } else {
                b = ld_h8(&Bsh[(nt * 16 + l15) * KPAD + ks * 32 + q * 8]);
            }
            acc[0][nt] = __builtin_amdgcn_mfma_f32_16x16x32_f16(a0, b, acc[0][nt], 0, 0, 0);
            acc[1][nt] = __builtin_amdgcn_mfma_f32_16x16x32_f16(a1, b, acc[1][nt], 0, 0, 0);
        }
    }

#pragma unroll
    for (int nt = 0; nt < 8; nt++) {
        const int col = nt * 16 + l15;
        const float bv = bias[col];
#pragma unroll
        for (int t = 0; t < 2; t++)
#pragma unroll
            for (int r = 0; r < 4; r++) {
                const int node = nbase + t * 16 + q * 4 + r;
                if (node < N_NODES) {
                    float v = fmaxf(acc[t][nt][r] + bv, 0.f);
                    outtab[(size_t)node * 128 + col] = (_Float16)v;
                }
            }
    }
}

// ---------------- edge predictor kernel (unchanged) ----------------
__launch_bounds__(256)
__global__ void pred_kernel(const _Float16* __restrict__ h2,
                            const int* __restrict__ src,
                            const int* __restrict__ dst,
                            const _Float16* __restrict__ W1t,  // [128][256] unpadded
                            const float* __restrict__ b1,
                            const float* __restrict__ W2,      // [128][2] fp32
                            const float* __restrict__ b2,
                            float* __restrict__ out)
{
    __shared__ __align__(16) _Float16 Bsh[128 * 256];

    const int tid = threadIdx.x;
    {
        const uint4* s4 = (const uint4*)W1t;
        uint4* d4 = (uint4*)Bsh;
        for (int i = tid; i < 4096; i += 256) {
            int n = i >> 5, c = i & 31;
            d4[(n << 5) | (c ^ (n & 31))] = s4[i];
        }
    }
    __syncthreads();

    const int wave = tid >> 6, lane = tid & 63;
    const int q = lane >> 4, l15 = lane & 15;
    const int ebase = blockIdx.x * 128 + wave * 32;

    const int e0 = ebase + l15, e1 = ebase + 16 + l15;
    const _Float16* rs0 = h2 + (size_t)src[e0] * 128;
    const _Float16* rd0 = h2 + (size_t)dst[e0] * 128;
    const _Float16* rs1 = h2 + (size_t)src[e1] * 128;
    const _Float16* rd1 = h2 + (size_t)dst[e1] * 128;

    f4 acc[2][8];
#pragma unroll
    for (int t = 0; t < 2; t++)
#pragma unroll
        for (int nt = 0; nt < 8; nt++) acc[t][nt] = (f4){0.f, 0.f, 0.f, 0.f};

#pragma unroll
    for (int ks = 0; ks < 8; ks++) {
        h8 a0, a1;
        if (ks < 4) {
            a0 = ld_h8(rs0 + ks * 32 + q * 8);
            a1 = ld_h8(rs1 + ks * 32 + q * 8);
        } else {
            a0 = ld_h8(rd0 + (ks - 4) * 32 + q * 8);
            a1 = ld_h8(rd1 + (ks - 4) * 32 + q * 8);
        }
#pragma unroll
        for (int nt = 0; nt < 8; nt++) {
            const int nrow = nt * 16 + l15;
            const int chunk = ((ks << 2) | q) ^ (nrow & 31);
            h8 b = ld_h8(Bsh + (((nrow << 5) | chunk) << 3));
            acc[0][nt] = __builtin_amdgcn_mfma_f32_16x16x32_f16(a0, b, acc[0][nt], 0, 0, 0);
            acc[1][nt] = __builtin_amdgcn_mfma_f32_16x16x32_f16(a1, b, acc[1][nt], 0, 0, 0);
        }
    }

    float o[2][4][2];
#pragma unroll
    for (int t = 0; t < 2; t++)
#pragma unroll
        for (int r = 0; r < 4; r++) { o[t][r][0] = 0.f; o[t][r][1] = 0.f; }

#pragma unroll
    for (int nt = 0; nt < 8; nt++) {
        const int nrow = nt * 16 + l15;
        const float bv = b1[nrow];
        const float w20 = W2[nrow * 2 + 0];
        const float w21 = W2[nrow * 2 + 1];
#pragma unroll
        for (int t = 0; t < 2; t++)
#pragma unroll
            for (int r = 0; r < 4; r++) {
                float y = fmaxf(acc[t][nt][r] + bv, 0.f);
                o[t][r][0] += y * w20;
                o[t][r][1] += y * w21;
            }
    }

#pragma unroll
    for (int m = 1; m < 16; m <<= 1) {
#pragma unroll
        for (int t = 0; t < 2; t++)
#pragma unroll
            for (int r = 0; r < 4; r++) {
                o[t][r][0] += __shfl_xor(o[t][r][0], m, 64);
                o[t][r][1] += __shfl_xor(o[t][r][1], m, 64);
            }
    }

    if (l15 < 8) {
        const int r = l15 >> 1, c = l15 & 1;
        const float bb = c ? b2[1] : b2[0];
#pragma unroll
        for (int t = 0; t < 2; t++) {
            float v0 = (r == 0) ? o[t][0][0] : (r == 1) ? o[t][1][0] : (r == 2) ? o[t][2][0] : o[t][3][0];
            float v1 = (r == 0) ? o[t][0][1] : (r == 1) ? o[t][1][1] : (r == 2) ? o[t][2][1] : o[t][3][1];
            float v = (c ? v1 : v0) + bb;
            out[(size_t)(ebase + t * 16 + q * 4 + r) * 2 + c] = v;
        }
    }
}

// ---------------- launch ----------------

extern "C" void kernel_launch(void* const* d_in, const int* in_sizes, int n_in,
                              void* d_out, int out_size, void* d_ws, size_t ws_size,
                              hipStream_t stream)
{
    const float* nfeats = (const float*)d_in[0];
    const float* efeats = (const float*)d_in[1];
    const int*   src    = (const int*)d_in[2];
    const int*   dst    = (const int*)d_in[3];
    const float* Wm1 = (const float*)d_in[4],  *bm1 = (const float*)d_in[5];
    const float* Wa1 = (const float*)d_in[6],  *ba1 = (const float*)d_in[7];
    const float* Wm2 = (const float*)d_in[8],  *bm2 = (const float*)d_in[9];
    const float* Wa2 = (const float*)d_in[10], *ba2 = (const float*)d_in[11];
    const float* W1  = (const float*)d_in[12], *b1  = (const float*)d_in[13];
    const float* W2  = (const float*)d_in[14], *b2  = (const float*)d_in[15];
    float* out = (float*)d_out;

    char* ws = (char*)d_ws;
    float*     s     = (float*)(ws);                   // 25,600,000 B
    int*       cnt   = (int*)(ws + 25600000);          //    200,000 B
    int*       tmp   = (int*)(ws + 25800000);          //    200,000 B
    int*       cursor= (int*)(ws + 26000000);          //    200,000 B
    int*       bsum  = (int*)(ws + 26200000);          //      1,024 B
    int*       bbase = (int*)(ws + 26201024);          //      1,024 B
    _Float16*  nf16  = (_Float16*)(ws + 26202048);     //  6,400,000 B
    int2*      pairs = (int2*)(ws + 32602048);         // 12,800,000 B (edge_id, src) per sorted slot
    int*       dsts  = (int*)(ws + 45402048);          //  6,400,000 B dst per sorted slot
    _Float16*  h1    = (_Float16*)(ws + 51802048);     // 12,800,000 B
    _Float16*  h2    = (_Float16*)(ws + 26202048);     // 12,800,000 B (aliases nf16 + pairs head; both dead by apply2)
    _Float16*  Wm1t  = (_Float16*)(ws + 64602048);     //     24,576 B (msg image, K=96)
    _Float16*  Wa1t  = (_Float16*)(ws + 64626624);     //     51,200 B
    _Float16*  Wm2t  = (_Float16*)(ws + 64677824);     //     40,960 B (msg image, K=160)
    _Float16*  Wa2t  = (_Float16*)(ws + 64718784);     //     65,536 B
    _Float16*  W1t   = (_Float16*)(ws + 64784320);     //     65,536 B  -> end 64,849,856

    hipMemsetAsync(s, 0, 25600000, stream);
    hipMemsetAsync(cnt, 0, 200000, stream);

    prep_weights<<<480, 256, 0, stream>>>(Wm1, Wa1, Wm2, Wa2, W1, Wm1t, Wa1t, Wm2t, Wa2t, W1t);
    cvt_nfeats<<<12500, 256, 0, stream>>>(nfeats, nf16);

    // counting sort of edges by dst
    hist_kernel<<<6250, 256, 0, stream>>>(dst, cnt);
    scan1_kernel<<<196, 256, 0, stream>>>(cnt, tmp, bsum);
    scan2_kernel<<<1, 256, 0, stream>>>(bsum, bbase);
    scan3_kernel<<<196, 256, 0, stream>>>(cnt, tmp, bbase, cursor);
    scatter_kernel<<<6250, 256, 0, stream>>>(src, dst, cursor, pairs, dsts);

    // layer 1 (LDS 33792 B -> 4 blocks/CU)
    msg_kernel_sorted<64, 5><<<12500, 256, 0, stream>>>(nf16, efeats, pairs, dsts, Wm1t, bm1, s);
    apply_kernel<64, false, 200><<<391, 256, 0, stream>>>(nf16, s, cnt, Wa1t, ba1, h1);

    // layer 2 (LDS 40960 B = exactly 4 blocks/CU)
    hipMemsetAsync(s, 0, 25600000, stream);
    msg_kernel_sorted<128, 4><<<12500, 256, 0, stream>>>(h1, efeats, pairs, dsts, Wm2t, bm2, s);
    apply_kernel<128, true, 256><<<391, 256, 0, stream>>>(h1, s, cnt, Wa2t, ba2, h2);

    // predictor
    pred_kernel<<<12500, 256, 0, stream>>>(h2, src, dst, W1t, b1, W2, b2, out);
}

// Round 3
// 1042.621 us; speedup vs baseline: 1.4223x; 1.0598x over previous
//
#include <hip/hip_runtime.h>

#define N_NODES 50000
#define N_EDGES 1600000

typedef _Float16 h8 __attribute__((ext_vector_type(8)));
typedef float f4 __attribute__((ext_vector_type(4)));

__device__ inline h8 ld_h8(const _Float16* p) { return *(const h8*)p; }

__device__ inline h8 cvt2h8(f4 a, f4 b) {
    h8 r;
    r[0] = (_Float16)a[0]; r[1] = (_Float16)a[1]; r[2] = (_Float16)a[2]; r[3] = (_Float16)a[3];
    r[4] = (_Float16)b[0]; r[5] = (_Float16)b[1]; r[6] = (_Float16)b[2]; r[7] = (_Float16)b[3];
    return r;
}

// ---------------- prep kernels ----------------
// Wm1/Wm2 are emitted as the final LDS image for the msg kernel:
//   img[(ks*128 + o)*32 + (q ^ ((o>>1)&3))*8 + j] = W[(ks*32 + q*8 + j)*128 + o]
// XOR chunk swizzle -> uniform 2-way LDS bank access on ds_read_b128 (free).

__global__ void prep_weights(const float* __restrict__ Wm1, const float* __restrict__ Wa1,
                             const float* __restrict__ Wm2, const float* __restrict__ Wa2,
                             const float* __restrict__ W1,
                             _Float16* __restrict__ Wm1t, _Float16* __restrict__ Wa1t,
                             _Float16* __restrict__ Wm2t, _Float16* __restrict__ Wa2t,
                             _Float16* __restrict__ W1t)
{
    int i = blockIdx.x * 256 + threadIdx.x;
    if (i < 12288) {                       // Wm1: 128*96, msg-swizzled image
        int o = i / 96, k = i % 96;
        int ks = k >> 5, q = (k >> 3) & 3, j = k & 7;
        int c = q ^ ((o >> 1) & 3);
        Wm1t[(ks * 128 + o) * 32 + c * 8 + j] = (_Float16)Wm1[k * 128 + o];
    } else if (i < 36864) {                // + 128*192 (Wa1, unchanged layout)
        int jj = i - 12288; int o = jj / 192, k = jj % 192;
        Wa1t[o * 200 + k] = (_Float16)Wa1[k * 128 + o];
    } else if (i < 57344) {                // + 128*160 (Wm2, msg-swizzled image)
        int jj = i - 36864; int o = jj / 160, k = jj % 160;
        int ks = k >> 5, q = (k >> 3) & 3, j = k & 7;
        int c = q ^ ((o >> 1) & 3);
        Wm2t[(ks * 128 + o) * 32 + c * 8 + j] = (_Float16)Wm2[k * 128 + o];
    } else if (i < 90112) {                // + 128*256 (Wa2, unchanged)
        int jj = i - 57344; int o = jj >> 8, k = jj & 255;
        Wa2t[(o << 8) + k] = (_Float16)Wa2[k * 128 + o];
    } else if (i < 122880) {               // + 128*256 (W1, unchanged)
        int jj = i - 90112; int o = jj >> 8, k = jj & 255;
        W1t[(o << 8) + k] = (_Float16)W1[k * 128 + o];
    }
}

__global__ void cvt_nfeats(const float* __restrict__ nf, _Float16* __restrict__ nf16)
{
    int i = blockIdx.x * 256 + threadIdx.x;   // exactly N*64 = 3.2M threads
    nf16[i] = (_Float16)nf[i];
}

// ---------------- counting sort of edges by dst ----------------

__global__ void hist_kernel(const int* __restrict__ dst, int* __restrict__ cnt)
{
    int e = blockIdx.x * 256 + threadIdx.x;   // exactly E threads
    atomicAdd(cnt + dst[e], 1);
}

__global__ void scan1_kernel(const int* __restrict__ cnt, int* __restrict__ tmp,
                             int* __restrict__ bsum)
{
    __shared__ int sh[256];
    int t = threadIdx.x, i = blockIdx.x * 256 + t;
    int v = (i < N_NODES) ? cnt[i] : 0;
    sh[t] = v; __syncthreads();
    for (int off = 1; off < 256; off <<= 1) {
        int x = (t >= off) ? sh[t - off] : 0;
        __syncthreads();
        sh[t] += x;
        __syncthreads();
    }
    if (i < N_NODES) tmp[i] = sh[t];
    if (t == 255) bsum[blockIdx.x] = sh[255];
}

__global__ void scan2_kernel(const int* __restrict__ bsum, int* __restrict__ bbase)
{
    __shared__ int sh[256];
    int t = threadIdx.x;
    int v = (t < 196) ? bsum[t] : 0;
    sh[t] = v; __syncthreads();
    for (int off = 1; off < 256; off <<= 1) {
        int x = (t >= off) ? sh[t - off] : 0;
        __syncthreads();
        sh[t] += x;
        __syncthreads();
    }
    if (t < 196) bbase[t] = sh[t] - v;   // exclusive
}

__global__ void scan3_kernel(const int* __restrict__ cnt, const int* __restrict__ tmp,
                             const int* __restrict__ bbase, int* __restrict__ cursor)
{
    int t = threadIdx.x, b = blockIdx.x, i = b * 256 + t;
    if (i < N_NODES) cursor[i] = tmp[i] - cnt[i] + bbase[b];
}

// scatter materializes, in dst-sorted slot order:
//   pairs[pos] = (edge_id, src_node)   -- one 8-B load in msg gets both
//   dsts[pos]  = dst_node              -- coalesced int4 loads for the reduce
__global__ void scatter_kernel(const int* __restrict__ src, const int* __restrict__ dst,
                               int* __restrict__ cursor,
                               int2* __restrict__ pairs, int* __restrict__ dsts)
{
    int e = blockIdx.x * 256 + threadIdx.x;   // exactly E threads
    int d = dst[e];
    int pos = atomicAdd(cursor + d, 1);
    pairs[pos] = make_int2(e, src[e]);
    dsts[pos] = d;
}

// ---------------- edge message kernel ----------------
// Block = 128 dst-sorted edge slots, 4 waves x 32 slots. LDS holds the swizzled
// B image during the GEMM; after one barrier it is reused as per-wave scratch
// for the rare mixed-dst reduce path. Segmented reduce hierarchy (dsts sorted,
// so first==last implies uniform):
//   32-row uniform (p~38%): 2 dense 64-lane atomics per wave
//   16-row uniform:         2 dense 64-lane atomics per group
//   mixed 16-row  (p~38%):  spill to wave-private LDS scratch, column-serial
//                           run-length scan with WAVE-UNIFORM branches ->
//                           every boundary emits 2 dense 64-lane atomics.
template<int KSRC_H, int MINW>
__launch_bounds__(256, MINW)
__global__ void msg_kernel_sorted(const _Float16* __restrict__ ntab,
                                  const float* __restrict__ efeats,
                                  const int2* __restrict__ pairs,
                                  const int* __restrict__ dsts,
                                  const _Float16* __restrict__ Wt,
                                  const float* __restrict__ bias,
                                  float* __restrict__ sacc)
{
    constexpr int EFSTEP = KSRC_H / 32;
    constexpr int KSTEPS = EFSTEP + 1;
    constexpr int BH = (KSRC_H + 32) * 128;              // fp16 elems
    constexpr int BBYTES = BH * 2;
    constexpr int SCRBYTES = 4 * 16 * 132 * 4;           // 33792
    constexpr int LDSBYTES = BBYTES > SCRBYTES ? BBYTES : SCRBYTES;
    __shared__ __align__(16) char smem[LDSBYTES];
    _Float16* Bsh = (_Float16*)smem;

    const int tid = threadIdx.x;
    const int wave = tid >> 6, lane = tid & 63;
    const int q = lane >> 4, l15 = lane & 15;
    const int wbase = blockIdx.x * 128 + wave * 32;

    // ---- early-issued gathers: overlap with B staging below ----
    const int2 p0 = pairs[wbase + l15];
    const int2 p1 = pairs[wbase + 16 + l15];
    const _Float16* r0 = ntab + (size_t)p0.y * KSRC_H + q * 8;
    const _Float16* r1 = ntab + (size_t)p1.y * KSRC_H + q * 8;
    h8 a0p = ld_h8(r0);
    h8 a1p = ld_h8(r1);
    const float* ep0 = efeats + (size_t)p0.x * 32 + q * 8;
    const float* ep1 = efeats + (size_t)p1.x * 32 + q * 8;
    f4 e0a, e0b, e1a, e1b;
    if constexpr (KSRC_H > 64) {       // L2 has VGPR headroom: prefetch efeats too
        e0a = *(const f4*)ep0; e0b = *(const f4*)(ep0 + 4);
        e1a = *(const f4*)ep1; e1b = *(const f4*)(ep1 + 4);
    }

    // ---- stage B (linear copy; image pre-swizzled on host side) ----
    {
        const uint4* s4 = (const uint4*)Wt;
        uint4* d4 = (uint4*)smem;
        constexpr int n4 = BH / 8;
        for (int i = tid; i < n4; i += 256) d4[i] = s4[i];
    }
    __syncthreads();

    f4 acc[2][8];
#pragma unroll
    for (int t = 0; t < 2; t++)
#pragma unroll
        for (int nt = 0; nt < 8; nt++) acc[t][nt] = (f4){0.f, 0.f, 0.f, 0.f};

    const _Float16* bp = Bsh + l15 * 32 + ((q ^ ((l15 >> 1) & 3)) << 3);
#pragma unroll
    for (int ks = 0; ks < KSTEPS; ks++) {
        h8 a0, a1;
        if (ks == 0) {
            a0 = a0p; a1 = a1p;
        } else if (ks < EFSTEP) {
            a0 = ld_h8(r0 + ks * 32);
            a1 = ld_h8(r1 + ks * 32);
        } else {
            if constexpr (KSRC_H > 64) {
                a0 = cvt2h8(e0a, e0b);
                a1 = cvt2h8(e1a, e1b);
            } else {
                a0 = cvt2h8(*(const f4*)ep0, *(const f4*)(ep0 + 4));
                a1 = cvt2h8(*(const f4*)ep1, *(const f4*)(ep1 + 4));
            }
        }
#pragma unroll
        for (int nt = 0; nt < 8; nt++) {
            h8 b = ld_h8(bp + ks * 4096 + nt * 512);
            acc[0][nt] = __builtin_amdgcn_mfma_f32_16x16x32_f16(a0, b, acc[0][nt], 0, 0, 0);
            acc[1][nt] = __builtin_amdgcn_mfma_f32_16x16x32_f16(a1, b, acc[1][nt], 0, 0, 0);
        }
    }

    __syncthreads();   // B image dead everywhere; smem becomes per-wave scratch

    // ---- segmented reduce ----
    float* wsch = (float*)smem + wave * 2112;   // 16*132 floats per wave

    float bv[8];
#pragma unroll
    for (int nt = 0; nt < 8; nt++) bv[nt] = bias[nt * 16 + l15];

    const int4 dv0 = *(const int4*)(dsts + wbase + q * 4);
    const int4 dv1 = *(const int4*)(dsts + wbase + 16 + q * 4);
    const int df0 = __shfl(dv0.x, l15, 64);        // dst of row wbase+0
    const int dl0 = __shfl(dv0.w, 48 + l15, 64);   // dst of row wbase+15
    const int df1 = __shfl(dv1.x, l15, 64);        // dst of row wbase+16
    const int dl1 = __shfl(dv1.w, 48 + l15, 64);   // dst of row wbase+31

    auto reduce16 = [&](const f4 (&a)[8], int df, int dl, int rbase) {
        if (df == dl) {
            float sv[8];
#pragma unroll
            for (int nt = 0; nt < 8; nt++) {
                float s = fmaxf(a[nt][0] + bv[nt], 0.f) + fmaxf(a[nt][1] + bv[nt], 0.f)
                        + fmaxf(a[nt][2] + bv[nt], 0.f) + fmaxf(a[nt][3] + bv[nt], 0.f);
                s += __shfl_xor(s, 16, 64);
                s += __shfl_xor(s, 32, 64);
                sv[nt] = s;
            }
#pragma unroll
            for (int i = 0; i < 2; i++) {
                float x = (q == 0) ? sv[i*4] : (q == 1) ? sv[i*4+1] : (q == 2) ? sv[i*4+2] : sv[i*4+3];
                atomicAdd(sacc + (size_t)df * 128 + i * 64 + lane, x);
            }
        } else {
            // mixed group: spill to wave scratch, column-serial uniform scan
#pragma unroll
            for (int nt = 0; nt < 8; nt++)
#pragma unroll
                for (int r = 0; r < 4; r++)
                    wsch[(q * 4 + r) * 132 + nt * 16 + l15] = fmaxf(a[nt][r] + bv[nt], 0.f);
            const int rb = __builtin_amdgcn_readfirstlane(rbase);
            float s0 = 0.f, s1 = 0.f;
            int dp = dsts[rb];
            for (int rr = 0; rr < 16; rr++) {
                const int d = dsts[rb + rr];          // wave-uniform scalar load
                const float v0 = wsch[rr * 132 + lane];
                const float v1 = wsch[rr * 132 + 64 + lane];
                if (d != dp) {                         // wave-uniform branch
                    atomicAdd(sacc + (size_t)dp * 128 + lane, s0);
                    atomicAdd(sacc + (size_t)dp * 128 + 64 + lane, s1);
                    s0 = v0; s1 = v1; dp = d;
                } else {
                    s0 += v0; s1 += v1;
                }
            }
            atomicAdd(sacc + (size_t)dp * 128 + lane, s0);
            atomicAdd(sacc + (size_t)dp * 128 + 64 + lane, s1);
        }
    };

    if (df0 == dl1) {
        // whole 32-row wave segment is one dst (sorted -> uniform)
        float sv[8];
#pragma unroll
        for (int nt = 0; nt < 8; nt++) {
            float s = fmaxf(acc[0][nt][0] + bv[nt], 0.f) + fmaxf(acc[0][nt][1] + bv[nt], 0.f)
                    + fmaxf(acc[0][nt][2] + bv[nt], 0.f) + fmaxf(acc[0][nt][3] + bv[nt], 0.f)
                    + fmaxf(acc[1][nt][0] + bv[nt], 0.f) + fmaxf(acc[1][nt][1] + bv[nt], 0.f)
                    + fmaxf(acc[1][nt][2] + bv[nt], 0.f) + fmaxf(acc[1][nt][3] + bv[nt], 0.f);
            s += __shfl_xor(s, 16, 64);
            s += __shfl_xor(s, 32, 64);
            sv[nt] = s;
        }
#pragma unroll
        for (int i = 0; i < 2; i++) {
            float x = (q == 0) ? sv[i*4] : (q == 1) ? sv[i*4+1] : (q == 2) ? sv[i*4+2] : sv[i*4+3];
            atomicAdd(sacc + (size_t)df0 * 128 + i * 64 + lane, x);
        }
    } else {
        reduce16(acc[0], df0, dl0, wbase);
        reduce16(acc[1], df1, dl1, wbase + 16);
    }
}

// ---------------- node apply kernel (unchanged) ----------------
template<int KSRC_H, bool SWIZ, int KPAD>
__launch_bounds__(256)
__global__ void apply_kernel(const _Float16* __restrict__ ntab,
                             const float* __restrict__ sacc,
                             const int* __restrict__ cnt,
                             const _Float16* __restrict__ Wt,
                             const float* __restrict__ bias,
                             _Float16* __restrict__ outtab)
{
    constexpr int KSTEPS = (KSRC_H + 128) / 32;
    __shared__ __align__(16) _Float16 Bsh[128 * KPAD];

    const int tid = threadIdx.x;
    if (SWIZ) {
        const uint4* s4 = (const uint4*)Wt;
        uint4* d4 = (uint4*)Bsh;
        for (int i = tid; i < 4096; i += 256) {
            int n = i >> 5, c = i & 31;
            d4[(n << 5) | (c ^ (n & 31))] = s4[i];
        }
    } else {
        const uint4* s4 = (const uint4*)Wt;
        uint4* d4 = (uint4*)Bsh;
        constexpr int n4 = 128 * KPAD / 8;
        for (int i = tid; i < n4; i += 256) d4[i] = s4[i];
    }
    __syncthreads();

    const int wave = tid >> 6, lane = tid & 63;
    const int q = lane >> 4, l15 = lane & 15;
    const int nbase = blockIdx.x * 128 + wave * 32;

    const int n0 = nbase + l15, n1 = nbase + 16 + l15;
    const int n0c = min(n0, N_NODES - 1), n1c = min(n1, N_NODES - 1);
    const _Float16* r0 = ntab + (size_t)n0c * KSRC_H;
    const _Float16* r1 = ntab + (size_t)n1c * KSRC_H;
    const float rcp0 = 1.0f / fmaxf((float)cnt[n0c], 1.0f);
    const float rcp1 = 1.0f / fmaxf((float)cnt[n1c], 1.0f);

    f4 acc[2][8];
#pragma unroll
    for (int t = 0; t < 2; t++)
#pragma unroll
        for (int nt = 0; nt < 8; nt++) acc[t][nt] = (f4){0.f, 0.f, 0.f, 0.f};

#pragma unroll
    for (int ks = 0; ks < KSTEPS; ks++) {
        h8 a0, a1;
        if (ks < KSRC_H / 32) {
            a0 = ld_h8(r0 + ks * 32 + q * 8);
            a1 = ld_h8(r1 + ks * 32 + q * 8);
        } else {
            const int kk = ks * 32 - KSRC_H + q * 8;
            const float* p0 = sacc + (size_t)n0c * 128 + kk;
            const float* p1 = sacc + (size_t)n1c * 128 + kk;
            f4 u0 = *(const f4*)p0 * rcp0, v0 = *(const f4*)(p0 + 4) * rcp0;
            f4 u1 = *(const f4*)p1 * rcp1, v1 = *(const f4*)(p1 + 4) * rcp1;
            a0 = cvt2h8(u0, v0);
            a1 = cvt2h8(u1, v1);
        }
#pragma unroll
        for (int nt = 0; nt < 8; nt++) {
            h8 b;
            if (SWIZ) {
                const int nrow = nt * 16 + l15;
                const int chunk = ((ks << 2) | q) ^ (nrow & 31);
                b = ld_h8(Bsh + (((nrow << 5) | chunk) << 3));
            } else {
                b = ld_h8(&Bsh[(nt * 16 + l15) * KPAD + ks * 32 + q * 8]);
            }
            acc[0][nt] = __builtin_amdgcn_mfma_f32_16x16x32_f16(a0, b, acc[0][nt], 0, 0, 0);
            acc[1][nt] = __builtin_amdgcn_mfma_f32_16x16x32_f16(a1, b, acc[1][nt], 0, 0, 0);
        }
    }

#pragma unroll
    for (int nt = 0; nt < 8; nt++) {
        const int col = nt * 16 + l15;
        const float bv = bias[col];
#pragma unroll
        for (int t = 0; t < 2; t++)
#pragma unroll
            for (int r = 0; r < 4; r++) {
                const int node = nbase + t * 16 + q * 4 + r;
                if (node < N_NODES) {
                    float v = fmaxf(acc[t][nt][r] + bv, 0.f);
                    outtab[(size_t)node * 128 + col] = (_Float16)v;
                }
            }
    }
}

// ---------------- edge predictor, dst-sorted slot order ----------------
// Slots follow the counting-sort order (pairs/dsts), so the h2[dst] gather is
// near-sequential with ~32x row reuse. B (W1, K=256) is staged in TWO 32-KB
// halves into the same LDS buffer (phase 0: src half k<128, phase 1: dst half)
// -> LDS 32768 B, occupancy cap 4-5 blocks/CU instead of 2. Output scatters
// by original edge id.
__launch_bounds__(256, 4)
__global__ void pred_kernel_sorted(const _Float16* __restrict__ h2,
                                   const int2* __restrict__ pairs,
                                   const int* __restrict__ dsts,
                                   const _Float16* __restrict__ W1t,  // [128 out][256 k]
                                   const float* __restrict__ b1,
                                   const float* __restrict__ W2,      // [128][2] fp32
                                   const float* __restrict__ b2,
                                   float* __restrict__ out)
{
    __shared__ __align__(16) _Float16 Bsh[128 * 128];   // 32 KB, one K-half

    const int tid = threadIdx.x;
    const int wave = tid >> 6, lane = tid & 63;
    const int q = lane >> 4, l15 = lane & 15;
    const int ebase = blockIdx.x * 128 + wave * 32;

    // early gathers: src rows for phase 0 (random), dst row addresses
    const int2 p0 = pairs[ebase + l15];
    const int2 p1 = pairs[ebase + 16 + l15];
    const _Float16* rs0 = h2 + (size_t)p0.y * 128 + q * 8;
    const _Float16* rs1 = h2 + (size_t)p1.y * 128 + q * 8;
    h8 s0p = ld_h8(rs0);
    h8 s1p = ld_h8(rs1);
    const int d0 = dsts[ebase + l15];
    const int d1 = dsts[ebase + 16 + l15];
    const _Float16* rd0 = h2 + (size_t)d0 * 128 + q * 8;
    const _Float16* rd1 = h2 + (size_t)d1 * 128 + q * 8;

    // stage half 0 of B (k in [0,128)); 16-chunk xor swizzle per out-row
    {
        const uint4* s4 = (const uint4*)W1t;
        uint4* d4 = (uint4*)Bsh;
        for (int i = tid; i < 2048; i += 256) {
            int n = i >> 4, c = i & 15;
            d4[(n << 4) | (c ^ (n & 15))] = s4[n * 32 + c];
        }
    }
    __syncthreads();

    f4 acc[2][8];
#pragma unroll
    for (int t = 0; t < 2; t++)
#pragma unroll
        for (int nt = 0; nt < 8; nt++) acc[t][nt] = (f4){0.f, 0.f, 0.f, 0.f};

    // phase 0: ks 0..3, A = h2[src]
#pragma unroll
    for (int ks = 0; ks < 4; ks++) {
        h8 a0 = (ks == 0) ? s0p : ld_h8(rs0 + ks * 32);
        h8 a1 = (ks == 0) ? s1p : ld_h8(rs1 + ks * 32);
#pragma unroll
        for (int nt = 0; nt < 8; nt++) {
            const int nrow = nt * 16 + l15;
            const int chunk = ((ks << 2) | q) ^ (nrow & 15);
            h8 b = ld_h8(Bsh + (((nrow << 4) | chunk) << 3));
            acc[0][nt] = __builtin_amdgcn_mfma_f32_16x16x32_f16(a0, b, acc[0][nt], 0, 0, 0);
            acc[1][nt] = __builtin_amdgcn_mfma_f32_16x16x32_f16(a1, b, acc[1][nt], 0, 0, 0);
        }
    }

    // issue first dst-row loads so their latency hides under the restage
    h8 d0p = ld_h8(rd0);
    h8 d1p = ld_h8(rd1);

    __syncthreads();   // everyone done reading half 0

    // stage half 1 of B (k in [128,256))
    {
        const uint4* s4 = (const uint4*)W1t;
        uint4* d4 = (uint4*)Bsh;
        for (int i = tid; i < 2048; i += 256) {
            int n = i >> 4, c = i & 15;
            d4[(n << 4) | (c ^ (n & 15))] = s4[n * 32 + 16 + c];
        }
    }
    __syncthreads();

    // phase 1: ks 0..3 of dst half, A = h2[dst] (sorted -> heavy row reuse)
#pragma unroll
    for (int ks = 0; ks < 4; ks++) {
        h8 a0 = (ks == 0) ? d0p : ld_h8(rd0 + ks * 32);
        h8 a1 = (ks == 0) ? d1p : ld_h8(rd1 + ks * 32);
#pragma unroll
        for (int nt = 0; nt < 8; nt++) {
            const int nrow = nt * 16 + l15;
            const int chunk = ((ks << 2) | q) ^ (nrow & 15);
            h8 b = ld_h8(Bsh + (((nrow << 4) | chunk) << 3));
            acc[0][nt] = __builtin_amdgcn_mfma_f32_16x16x32_f16(a0, b, acc[0][nt], 0, 0, 0);
            acc[1][nt] = __builtin_amdgcn_mfma_f32_16x16x32_f16(a1, b, acc[1][nt], 0, 0, 0);
        }
    }

    float o[2][4][2];
#pragma unroll
    for (int t = 0; t < 2; t++)
#pragma unroll
        for (int r = 0; r < 4; r++) { o[t][r][0] = 0.f; o[t][r][1] = 0.f; }

#pragma unroll
    for (int nt = 0; nt < 8; nt++) {
        const int nrow = nt * 16 + l15;
        const float bv = b1[nrow];
        const float w20 = W2[nrow * 2 + 0];
        const float w21 = W2[nrow * 2 + 1];
#pragma unroll
        for (int t = 0; t < 2; t++)
#pragma unroll
            for (int r = 0; r < 4; r++) {
                float y = fmaxf(acc[t][nt][r] + bv, 0.f);
                o[t][r][0] += y * w20;
                o[t][r][1] += y * w21;
            }
    }

#pragma unroll
    for (int m = 1; m < 16; m <<= 1) {
#pragma unroll
        for (int t = 0; t < 2; t++)
#pragma unroll
            for (int r = 0; r < 4; r++) {
                o[t][r][0] += __shfl_xor(o[t][r][0], m, 64);
                o[t][r][1] += __shfl_xor(o[t][r][1], m, 64);
            }
    }

    if (l15 < 8) {
        const int r = l15 >> 1, c = l15 & 1;
        const float bb = c ? b2[1] : b2[0];
#pragma unroll
        for (int t = 0; t < 2; t++) {
            float v0 = (r == 0) ? o[t][0][0] : (r == 1) ? o[t][1][0] : (r == 2) ? o[t][2][0] : o[t][3][0];
            float v1 = (r == 0) ? o[t][0][1] : (r == 1) ? o[t][1][1] : (r == 2) ? o[t][2][1] : o[t][3][1];
            float v = (c ? v1 : v0) + bb;
            const int e = pairs[ebase + t * 16 + q * 4 + r].x;   // scatter by edge id
            out[(size_t)e * 2 + c] = v;
        }
    }
}

// ---------------- legacy predictor (fallback when ws too small) ----------------
__launch_bounds__(256)
__global__ void pred_kernel(const _Float16* __restrict__ h2,
                            const int* __restrict__ src,
                            const int* __restrict__ dst,
                            const _Float16* __restrict__ W1t,  // [128][256] unpadded
                            const float* __restrict__ b1,
                            const float* __restrict__ W2,      // [128][2] fp32
                            const float* __restrict__ b2,
                            float* __restrict__ out)
{
    __shared__ __align__(16) _Float16 Bsh[128 * 256];

    const int tid = threadIdx.x;
    {
        const uint4* s4 = (const uint4*)W1t;
        uint4* d4 = (uint4*)Bsh;
        for (int i = tid; i < 4096; i += 256) {
            int n = i >> 5, c = i & 31;
            d4[(n << 5) | (c ^ (n & 31))] = s4[i];
        }
    }
    __syncthreads();

    const int wave = tid >> 6, lane = tid & 63;
    const int q = lane >> 4, l15 = lane & 15;
    const int ebase = blockIdx.x * 128 + wave * 32;

    const int e0 = ebase + l15, e1 = ebase + 16 + l15;
    const _Float16* rs0 = h2 + (size_t)src[e0] * 128;
    const _Float16* rd0 = h2 + (size_t)dst[e0] * 128;
    const _Float16* rs1 = h2 + (size_t)src[e1] * 128;
    const _Float16* rd1 = h2 + (size_t)dst[e1] * 128;

    f4 acc[2][8];
#pragma unroll
    for (int t = 0; t < 2; t++)
#pragma unroll
        for (int nt = 0; nt < 8; nt++) acc[t][nt] = (f4){0.f, 0.f, 0.f, 0.f};

#pragma unroll
    for (int ks = 0; ks < 8; ks++) {
        h8 a0, a1;
        if (ks < 4) {
            a0 = ld_h8(rs0 + ks * 32 + q * 8);
            a1 = ld_h8(rs1 + ks * 32 + q * 8);
        } else {
            a0 = ld_h8(rd0 + (ks - 4) * 32 + q * 8);
            a1 = ld_h8(rd1 + (ks - 4) * 32 + q * 8);
        }
#pragma unroll
        for (int nt = 0; nt < 8; nt++) {
            const int nrow = nt * 16 + l15;
            const int chunk = ((ks << 2) | q) ^ (nrow & 31);
            h8 b = ld_h8(Bsh + (((nrow << 5) | chunk) << 3));
            acc[0][nt] = __builtin_amdgcn_mfma_f32_16x16x32_f16(a0, b, acc[0][nt], 0, 0, 0);
            acc[1][nt] = __builtin_amdgcn_mfma_f32_16x16x32_f16(a1, b, acc[1][nt], 0, 0, 0);
        }
    }

    float o[2][4][2];
#pragma unroll
    for (int t = 0; t < 2; t++)
#pragma unroll
        for (int r = 0; r < 4; r++) { o[t][r][0] = 0.f; o[t][r][1] = 0.f; }

#pragma unroll
    for (int nt = 0; nt < 8; nt++) {
        const int nrow = nt * 16 + l15;
        const float bv = b1[nrow];
        const float w20 = W2[nrow * 2 + 0];
        const float w21 = W2[nrow * 2 + 1];
#pragma unroll
        for (int t = 0; t < 2; t++)
#pragma unroll
            for (int r = 0; r < 4; r++) {
                float y = fmaxf(acc[t][nt][r] + bv, 0.f);
                o[t][r][0] += y * w20;
                o[t][r][1] += y * w21;
            }
    }

#pragma unroll
    for (int m = 1; m < 16; m <<= 1) {
#pragma unroll
        for (int t = 0; t < 2; t++)
#pragma unroll
            for (int r = 0; r < 4; r++) {
                o[t][r][0] += __shfl_xor(o[t][r][0], m, 64);
                o[t][r][1] += __shfl_xor(o[t][r][1], m, 64);
            }
    }

    if (l15 < 8) {
        const int r = l15 >> 1, c = l15 & 1;
        const float bb = c ? b2[1] : b2[0];
#pragma unroll
        for (int t = 0; t < 2; t++) {
            float v0 = (r == 0) ? o[t][0][0] : (r == 1) ? o[t][1][0] : (r == 2) ? o[t][2][0] : o[t][3][0];
            float v1 = (r == 0) ? o[t][0][1] : (r == 1) ? o[t][1][1] : (r == 2) ? o[t][2][1] : o[t][3][1];
            float v = (c ? v1 : v0) + bb;
            out[(size_t)(ebase + t * 16 + q * 4 + r) * 2 + c] = v;
        }
    }
}

// ---------------- launch ----------------

extern "C" void kernel_launch(void* const* d_in, const int* in_sizes, int n_in,
                              void* d_out, int out_size, void* d_ws, size_t ws_size,
                              hipStream_t stream)
{
    const float* nfeats = (const float*)d_in[0];
    const float* efeats = (const float*)d_in[1];
    const int*   src    = (const int*)d_in[2];
    const int*   dst    = (const int*)d_in[3];
    const float* Wm1 = (const float*)d_in[4],  *bm1 = (const float*)d_in[5];
    const float* Wa1 = (const float*)d_in[6],  *ba1 = (const float*)d_in[7];
    const float* Wm2 = (const float*)d_in[8],  *bm2 = (const float*)d_in[9];
    const float* Wa2 = (const float*)d_in[10], *ba2 = (const float*)d_in[11];
    const float* W1  = (const float*)d_in[12], *b1  = (const float*)d_in[13];
    const float* W2  = (const float*)d_in[14], *b2  = (const float*)d_in[15];
    float* out = (float*)d_out;

    char* ws = (char*)d_ws;
    float*     s     = (float*)(ws);                   // 25,600,000 B
    int*       cnt   = (int*)(ws + 25600000);          //    200,000 B
    int*       tmp   = (int*)(ws + 25800000);          //    200,000 B
    int*       cursor= (int*)(ws + 26000000);          //    200,000 B
    int*       bsum  = (int*)(ws + 26200000);          //      1,024 B
    int*       bbase = (int*)(ws + 26201024);          //      1,024 B
    _Float16*  nf16  = (_Float16*)(ws + 26202048);     //  6,400,000 B
    int2*      pairs = (int2*)(ws + 32602048);         // 12,800,000 B (edge_id, src) per sorted slot
    int*       dsts  = (int*)(ws + 45402048);          //  6,400,000 B dst per sorted slot
    _Float16*  h1    = (_Float16*)(ws + 51802048);     // 12,800,000 B
    _Float16*  Wm1t  = (_Float16*)(ws + 64602048);     //     24,576 B (msg image, K=96)
    _Float16*  Wa1t  = (_Float16*)(ws + 64626624);     //     51,200 B
    _Float16*  Wm2t  = (_Float16*)(ws + 64677824);     //     40,960 B (msg image, K=160)
    _Float16*  Wa2t  = (_Float16*)(ws + 64718784);     //     65,536 B
    _Float16*  W1t   = (_Float16*)(ws + 64784320);     //     65,536 B  -> 64,849,856

    // h2 placement: sorted pred needs pairs/dsts live -> fresh region if ws allows;
    // else alias nf16+pairs-head (round-2 layout) and use the legacy pred.
    const bool big_ws = ws_size >= (size_t)77800000;
    _Float16* h2 = big_ws ? (_Float16*)(ws + 64849920)   // +12,800,000 -> end 77,649,920
                          : (_Float16*)(ws + 26202048);

    hipMemsetAsync(s, 0, 25600000, stream);
    hipMemsetAsync(cnt, 0, 200000, stream);

    prep_weights<<<480, 256, 0, stream>>>(Wm1, Wa1, Wm2, Wa2, W1, Wm1t, Wa1t, Wm2t, Wa2t, W1t);
    cvt_nfeats<<<12500, 256, 0, stream>>>(nfeats, nf16);

    // counting sort of edges by dst
    hist_kernel<<<6250, 256, 0, stream>>>(dst, cnt);
    scan1_kernel<<<196, 256, 0, stream>>>(cnt, tmp, bsum);
    scan2_kernel<<<1, 256, 0, stream>>>(bsum, bbase);
    scan3_kernel<<<196, 256, 0, stream>>>(cnt, tmp, bbase, cursor);
    scatter_kernel<<<6250, 256, 0, stream>>>(src, dst, cursor, pairs, dsts);

    // layer 1 (LDS 33792 B -> 4 blocks/CU)
    msg_kernel_sorted<64, 5><<<12500, 256, 0, stream>>>(nf16, efeats, pairs, dsts, Wm1t, bm1, s);
    apply_kernel<64, false, 200><<<391, 256, 0, stream>>>(nf16, s, cnt, Wa1t, ba1, h1);

    // layer 2 (LDS 40960 B = exactly 4 blocks/CU)
    hipMemsetAsync(s, 0, 25600000, stream);
    msg_kernel_sorted<128, 4><<<12500, 256, 0, stream>>>(h1, efeats, pairs, dsts, Wm2t, bm2, s);
    apply_kernel<128, true, 256><<<391, 256, 0, stream>>>(h1, s, cnt, Wa2t, ba2, h2);

    // predictor
    if (big_ws)
        pred_kernel_sorted<<<12500, 256, 0, stream>>>(h2, pairs, dsts, W1t, b1, W2, b2, out);
    else
        pred_kernel<<<12500, 256, 0, stream>>>(h2, src, dst, W1t, b1, W2, b2, out);
}

// Round 4
// 1020.971 us; speedup vs baseline: 1.4525x; 1.0212x over previous
//
#include <hip/hip_runtime.h>

#define N_NODES 50000
#define N_EDGES 1600000

typedef _Float16 h8 __attribute__((ext_vector_type(8)));
typedef float f4 __attribute__((ext_vector_type(4)));

__device__ inline h8 ld_h8(const _Float16* p) { return *(const h8*)p; }

__device__ inline h8 cvt2h8(f4 a, f4 b) {
    h8 r;
    r[0] = (_Float16)a[0]; r[1] = (_Float16)a[1]; r[2] = (_Float16)a[2]; r[3] = (_Float16)a[3];
    r[4] = (_Float16)b[0]; r[5] = (_Float16)b[1]; r[6] = (_Float16)b[2]; r[7] = (_Float16)b[3];
    return r;
}

// ---------------- prep kernels ----------------
// Wm1/Wm2 are emitted as the final LDS image for the msg kernel:
//   img[(ks*128 + o)*32 + (q ^ ((o>>1)&3))*8 + j] = W[(ks*32 + q*8 + j)*128 + o]
// XOR chunk swizzle -> uniform 2-way LDS bank access on ds_read_b128 (free).

__global__ void prep_weights(const float* __restrict__ Wm1, const float* __restrict__ Wa1,
                             const float* __restrict__ Wm2, const float* __restrict__ Wa2,
                             const float* __restrict__ W1,
                             _Float16* __restrict__ Wm1t, _Float16* __restrict__ Wa1t,
                             _Float16* __restrict__ Wm2t, _Float16* __restrict__ Wa2t,
                             _Float16* __restrict__ W1t)
{
    int i = blockIdx.x * 256 + threadIdx.x;
    if (i < 12288) {                       // Wm1: 128*96, msg-swizzled image
        int o = i / 96, k = i % 96;
        int ks = k >> 5, q = (k >> 3) & 3, j = k & 7;
        int c = q ^ ((o >> 1) & 3);
        Wm1t[(ks * 128 + o) * 32 + c * 8 + j] = (_Float16)Wm1[k * 128 + o];
    } else if (i < 36864) {                // + 128*192 (Wa1, unchanged layout)
        int jj = i - 12288; int o = jj / 192, k = jj % 192;
        Wa1t[o * 200 + k] = (_Float16)Wa1[k * 128 + o];
    } else if (i < 57344) {                // + 128*160 (Wm2, msg-swizzled image)
        int jj = i - 36864; int o = jj / 160, k = jj % 160;
        int ks = k >> 5, q = (k >> 3) & 3, j = k & 7;
        int c = q ^ ((o >> 1) & 3);
        Wm2t[(ks * 128 + o) * 32 + c * 8 + j] = (_Float16)Wm2[k * 128 + o];
    } else if (i < 90112) {                // + 128*256 (Wa2, unchanged)
        int jj = i - 57344; int o = jj >> 8, k = jj & 255;
        Wa2t[(o << 8) + k] = (_Float16)Wa2[k * 128 + o];
    } else if (i < 122880) {               // + 128*256 (W1, unchanged)
        int jj = i - 90112; int o = jj >> 8, k = jj & 255;
        W1t[(o << 8) + k] = (_Float16)W1[k * 128 + o];
    }
}

__global__ void cvt_nfeats(const float* __restrict__ nf, _Float16* __restrict__ nf16)
{
    int i = blockIdx.x * 256 + threadIdx.x;   // exactly N*64 = 3.2M threads
    nf16[i] = (_Float16)nf[i];
}

// ---------------- counting sort of edges by dst ----------------

__global__ void hist_kernel(const int* __restrict__ dst, int* __restrict__ cnt)
{
    int e = blockIdx.x * 256 + threadIdx.x;   // exactly E threads
    atomicAdd(cnt + dst[e], 1);
}

__global__ void scan1_kernel(const int* __restrict__ cnt, int* __restrict__ tmp,
                             int* __restrict__ bsum)
{
    __shared__ int sh[256];
    int t = threadIdx.x, i = blockIdx.x * 256 + t;
    int v = (i < N_NODES) ? cnt[i] : 0;
    sh[t] = v; __syncthreads();
    for (int off = 1; off < 256; off <<= 1) {
        int x = (t >= off) ? sh[t - off] : 0;
        __syncthreads();
        sh[t] += x;
        __syncthreads();
    }
    if (i < N_NODES) tmp[i] = sh[t];
    if (t == 255) bsum[blockIdx.x] = sh[255];
}

__global__ void scan2_kernel(const int* __restrict__ bsum, int* __restrict__ bbase)
{
    __shared__ int sh[256];
    int t = threadIdx.x;
    int v = (t < 196) ? bsum[t] : 0;
    sh[t] = v; __syncthreads();
    for (int off = 1; off < 256; off <<= 1) {
        int x = (t >= off) ? sh[t - off] : 0;
        __syncthreads();
        sh[t] += x;
        __syncthreads();
    }
    if (t < 196) bbase[t] = sh[t] - v;   // exclusive
}

__global__ void scan3_kernel(const int* __restrict__ cnt, const int* __restrict__ tmp,
                             const int* __restrict__ bbase, int* __restrict__ cursor)
{
    int t = threadIdx.x, b = blockIdx.x, i = b * 256 + t;
    if (i < N_NODES) cursor[i] = tmp[i] - cnt[i] + bbase[b];
}

// scatter materializes, in dst-sorted slot order:
//   pairs[pos] = (edge_id, src_node)   -- one 8-B load in msg gets both
//   dsts[pos]  = dst_node              -- coalesced int4 loads for the reduce
__global__ void scatter_kernel(const int* __restrict__ src, const int* __restrict__ dst,
                               int* __restrict__ cursor,
                               int2* __restrict__ pairs, int* __restrict__ dsts)
{
    int e = blockIdx.x * 256 + threadIdx.x;   // exactly E threads
    int d = dst[e];
    int pos = atomicAdd(cursor + d, 1);
    pairs[pos] = make_int2(e, src[e]);
    dsts[pos] = d;
}

// ---------------- edge message kernel (unchanged from round 2) ----------------
template<int KSRC_H, int MINW>
__launch_bounds__(256, MINW)
__global__ void msg_kernel_sorted(const _Float16* __restrict__ ntab,
                                  const float* __restrict__ efeats,
                                  const int2* __restrict__ pairs,
                                  const int* __restrict__ dsts,
                                  const _Float16* __restrict__ Wt,
                                  const float* __restrict__ bias,
                                  float* __restrict__ sacc)
{
    constexpr int EFSTEP = KSRC_H / 32;
    constexpr int KSTEPS = EFSTEP + 1;
    constexpr int BH = (KSRC_H + 32) * 128;              // fp16 elems
    constexpr int BBYTES = BH * 2;
    constexpr int SCRBYTES = 4 * 16 * 132 * 4;           // 33792
    constexpr int LDSBYTES = BBYTES > SCRBYTES ? BBYTES : SCRBYTES;
    __shared__ __align__(16) char smem[LDSBYTES];
    _Float16* Bsh = (_Float16*)smem;

    const int tid = threadIdx.x;
    const int wave = tid >> 6, lane = tid & 63;
    const int q = lane >> 4, l15 = lane & 15;
    const int wbase = blockIdx.x * 128 + wave * 32;

    // ---- early-issued gathers: overlap with B staging below ----
    const int2 p0 = pairs[wbase + l15];
    const int2 p1 = pairs[wbase + 16 + l15];
    const _Float16* r0 = ntab + (size_t)p0.y * KSRC_H + q * 8;
    const _Float16* r1 = ntab + (size_t)p1.y * KSRC_H + q * 8;
    h8 a0p = ld_h8(r0);
    h8 a1p = ld_h8(r1);
    const float* ep0 = efeats + (size_t)p0.x * 32 + q * 8;
    const float* ep1 = efeats + (size_t)p1.x * 32 + q * 8;
    f4 e0a, e0b, e1a, e1b;
    if constexpr (KSRC_H > 64) {       // L2 has VGPR headroom: prefetch efeats too
        e0a = *(const f4*)ep0; e0b = *(const f4*)(ep0 + 4);
        e1a = *(const f4*)ep1; e1b = *(const f4*)(ep1 + 4);
    }

    // ---- stage B (linear copy; image pre-swizzled on host side) ----
    {
        const uint4* s4 = (const uint4*)Wt;
        uint4* d4 = (uint4*)smem;
        constexpr int n4 = BH / 8;
        for (int i = tid; i < n4; i += 256) d4[i] = s4[i];
    }
    __syncthreads();

    f4 acc[2][8];
#pragma unroll
    for (int t = 0; t < 2; t++)
#pragma unroll
        for (int nt = 0; nt < 8; nt++) acc[t][nt] = (f4){0.f, 0.f, 0.f, 0.f};

    const _Float16* bp = Bsh + l15 * 32 + ((q ^ ((l15 >> 1) & 3)) << 3);
#pragma unroll
    for (int ks = 0; ks < KSTEPS; ks++) {
        h8 a0, a1;
        if (ks == 0) {
            a0 = a0p; a1 = a1p;
        } else if (ks < EFSTEP) {
            a0 = ld_h8(r0 + ks * 32);
            a1 = ld_h8(r1 + ks * 32);
        } else {
            if constexpr (KSRC_H > 64) {
                a0 = cvt2h8(e0a, e0b);
                a1 = cvt2h8(e1a, e1b);
            } else {
                a0 = cvt2h8(*(const f4*)ep0, *(const f4*)(ep0 + 4));
                a1 = cvt2h8(*(const f4*)ep1, *(const f4*)(ep1 + 4));
            }
        }
#pragma unroll
        for (int nt = 0; nt < 8; nt++) {
            h8 b = ld_h8(bp + ks * 4096 + nt * 512);
            acc[0][nt] = __builtin_amdgcn_mfma_f32_16x16x32_f16(a0, b, acc[0][nt], 0, 0, 0);
            acc[1][nt] = __builtin_amdgcn_mfma_f32_16x16x32_f16(a1, b, acc[1][nt], 0, 0, 0);
        }
    }

    __syncthreads();   // B image dead everywhere; smem becomes per-wave scratch

    // ---- segmented reduce ----
    float* wsch = (float*)smem + wave * 2112;   // 16*132 floats per wave

    float bv[8];
#pragma unroll
    for (int nt = 0; nt < 8; nt++) bv[nt] = bias[nt * 16 + l15];

    const int4 dv0 = *(const int4*)(dsts + wbase + q * 4);
    const int4 dv1 = *(const int4*)(dsts + wbase + 16 + q * 4);
    const int df0 = __shfl(dv0.x, l15, 64);        // dst of row wbase+0
    const int dl0 = __shfl(dv0.w, 48 + l15, 64);   // dst of row wbase+15
    const int df1 = __shfl(dv1.x, l15, 64);        // dst of row wbase+16
    const int dl1 = __shfl(dv1.w, 48 + l15, 64);   // dst of row wbase+31

    auto reduce16 = [&](const f4 (&a)[8], int df, int dl, int rbase) {
        if (df == dl) {
            float sv[8];
#pragma unroll
            for (int nt = 0; nt < 8; nt++) {
                float s = fmaxf(a[nt][0] + bv[nt], 0.f) + fmaxf(a[nt][1] + bv[nt], 0.f)
                        + fmaxf(a[nt][2] + bv[nt], 0.f) + fmaxf(a[nt][3] + bv[nt], 0.f);
                s += __shfl_xor(s, 16, 64);
                s += __shfl_xor(s, 32, 64);
                sv[nt] = s;
            }
#pragma unroll
            for (int i = 0; i < 2; i++) {
                float x = (q == 0) ? sv[i*4] : (q == 1) ? sv[i*4+1] : (q == 2) ? sv[i*4+2] : sv[i*4+3];
                atomicAdd(sacc + (size_t)df * 128 + i * 64 + lane, x);
            }
        } else {
            // mixed group: spill to wave scratch, column-serial uniform scan
#pragma unroll
            for (int nt = 0; nt < 8; nt++)
#pragma unroll
                for (int r = 0; r < 4; r++)
                    wsch[(q * 4 + r) * 132 + nt * 16 + l15] = fmaxf(a[nt][r] + bv[nt], 0.f);
            const int rb = __builtin_amdgcn_readfirstlane(rbase);
            float s0 = 0.f, s1 = 0.f;
            int dp = dsts[rb];
            for (int rr = 0; rr < 16; rr++) {
                const int d = dsts[rb + rr];          // wave-uniform scalar load
                const float v0 = wsch[rr * 132 + lane];
                const float v1 = wsch[rr * 132 + 64 + lane];
                if (d != dp) {                         // wave-uniform branch
                    atomicAdd(sacc + (size_t)dp * 128 + lane, s0);
                    atomicAdd(sacc + (size_t)dp * 128 + 64 + lane, s1);
                    s0 = v0; s1 = v1; dp = d;
                } else {
                    s0 += v0; s1 += v1;
                }
            }
            atomicAdd(sacc + (size_t)dp * 128 + lane, s0);
            atomicAdd(sacc + (size_t)dp * 128 + 64 + lane, s1);
        }
    };

    if (df0 == dl1) {
        // whole 32-row wave segment is one dst (sorted -> uniform)
        float sv[8];
#pragma unroll
        for (int nt = 0; nt < 8; nt++) {
            float s = fmaxf(acc[0][nt][0] + bv[nt], 0.f) + fmaxf(acc[0][nt][1] + bv[nt], 0.f)
                    + fmaxf(acc[0][nt][2] + bv[nt], 0.f) + fmaxf(acc[0][nt][3] + bv[nt], 0.f)
                    + fmaxf(acc[1][nt][0] + bv[nt], 0.f) + fmaxf(acc[1][nt][1] + bv[nt], 0.f)
                    + fmaxf(acc[1][nt][2] + bv[nt], 0.f) + fmaxf(acc[1][nt][3] + bv[nt], 0.f);
            s += __shfl_xor(s, 16, 64);
            s += __shfl_xor(s, 32, 64);
            sv[nt] = s;
        }
#pragma unroll
        for (int i = 0; i < 2; i++) {
            float x = (q == 0) ? sv[i*4] : (q == 1) ? sv[i*4+1] : (q == 2) ? sv[i*4+2] : sv[i*4+3];
            atomicAdd(sacc + (size_t)df0 * 128 + i * 64 + lane, x);
        }
    } else {
        reduce16(acc[0], df0, dl0, wbase);
        reduce16(acc[1], df1, dl1, wbase + 16);
    }
}

// ---------------- node apply kernel (unchanged) ----------------
template<int KSRC_H, bool SWIZ, int KPAD>
__launch_bounds__(256)
__global__ void apply_kernel(const _Float16* __restrict__ ntab,
                             const float* __restrict__ sacc,
                             const int* __restrict__ cnt,
                             const _Float16* __restrict__ Wt,
                             const float* __restrict__ bias,
                             _Float16* __restrict__ outtab)
{
    constexpr int KSTEPS = (KSRC_H + 128) / 32;
    __shared__ __align__(16) _Float16 Bsh[128 * KPAD];

    const int tid = threadIdx.x;
    if (SWIZ) {
        const uint4* s4 = (const uint4*)Wt;
        uint4* d4 = (uint4*)Bsh;
        for (int i = tid; i < 4096; i += 256) {
            int n = i >> 5, c = i & 31;
            d4[(n << 5) | (c ^ (n & 31))] = s4[i];
        }
    } else {
        const uint4* s4 = (const uint4*)Wt;
        uint4* d4 = (uint4*)Bsh;
        constexpr int n4 = 128 * KPAD / 8;
        for (int i = tid; i < n4; i += 256) d4[i] = s4[i];
    }
    __syncthreads();

    const int wave = tid >> 6, lane = tid & 63;
    const int q = lane >> 4, l15 = lane & 15;
    const int nbase = blockIdx.x * 128 + wave * 32;

    const int n0 = nbase + l15, n1 = nbase + 16 + l15;
    const int n0c = min(n0, N_NODES - 1), n1c = min(n1, N_NODES - 1);
    const _Float16* r0 = ntab + (size_t)n0c * KSRC_H;
    const _Float16* r1 = ntab + (size_t)n1c * KSRC_H;
    const float rcp0 = 1.0f / fmaxf((float)cnt[n0c], 1.0f);
    const float rcp1 = 1.0f / fmaxf((float)cnt[n1c], 1.0f);

    f4 acc[2][8];
#pragma unroll
    for (int t = 0; t < 2; t++)
#pragma unroll
        for (int nt = 0; nt < 8; nt++) acc[t][nt] = (f4){0.f, 0.f, 0.f, 0.f};

#pragma unroll
    for (int ks = 0; ks < KSTEPS; ks++) {
        h8 a0, a1;
        if (ks < KSRC_H / 32) {
            a0 = ld_h8(r0 + ks * 32 + q * 8);
            a1 = ld_h8(r1 + ks * 32 + q * 8);
        } else {
            const int kk = ks * 32 - KSRC_H + q * 8;
            const float* p0 = sacc + (size_t)n0c * 128 + kk;
            const float* p1 = sacc + (size_t)n1c * 128 + kk;
            f4 u0 = *(const f4*)p0 * rcp0, v0 = *(const f4*)(p0 + 4) * rcp0;
            f4 u1 = *(const f4*)p1 * rcp1, v1 = *(const f4*)(p1 + 4) * rcp1;
            a0 = cvt2h8(u0, v0);
            a1 = cvt2h8(u1, v1);
        }
#pragma unroll
        for (int nt = 0; nt < 8; nt++) {
            h8 b;
            if (SWIZ) {
                const int nrow = nt * 16 + l15;
                const int chunk = ((ks << 2) | q) ^ (nrow & 31);
                b = ld_h8(Bsh + (((nrow << 5) | chunk) << 3));
            } else {
                b = ld_h8(&Bsh[(nt * 16 + l15) * KPAD + ks * 32 + q * 8]);
            }
            acc[0][nt] = __builtin_amdgcn_mfma_f32_16x16x32_f16(a0, b, acc[0][nt], 0, 0, 0);
            acc[1][nt] = __builtin_amdgcn_mfma_f32_16x16x32_f16(a1, b, acc[1][nt], 0, 0, 0);
        }
    }

#pragma unroll
    for (int nt = 0; nt < 8; nt++) {
        const int col = nt * 16 + l15;
        const float bv = bias[col];
#pragma unroll
        for (int t = 0; t < 2; t++)
#pragma unroll
            for (int r = 0; r < 4; r++) {
                const int node = nbase + t * 16 + q * 4 + r;
                if (node < N_NODES) {
                    float v = fmaxf(acc[t][nt][r] + bv, 0.f);
                    outtab[(size_t)node * 128 + col] = (_Float16)v;
                }
            }
    }
}

// ---------------- per-node predictor halves ----------------
// P[n] = h2[n] @ W1[0:128,:]          (fp16, gathered later by src)
// Q[n] = h2[n] @ W1[128:256,:] + b1   (fp32, streamed later by sorted dst)
// One A-load feeds both halves (same h2 row against two B-halves).
__launch_bounds__(256)
__global__ void node_pq_kernel(const _Float16* __restrict__ h2,
                               const _Float16* __restrict__ W1t,  // [128 out][256 k] image
                               const float* __restrict__ b1,
                               _Float16* __restrict__ P,
                               float* __restrict__ Q)
{
    __shared__ __align__(16) _Float16 Bsh[128 * 256];

    const int tid = threadIdx.x;
    {
        const uint4* s4 = (const uint4*)W1t;
        uint4* d4 = (uint4*)Bsh;
        for (int i = tid; i < 4096; i += 256) {
            int n = i >> 5, c = i & 31;
            d4[(n << 5) | (c ^ (n & 31))] = s4[i];
        }
    }
    __syncthreads();

    const int wave = tid >> 6, lane = tid & 63;
    const int q = lane >> 4, l15 = lane & 15;
    const int nbase = blockIdx.x * 128 + wave * 32;

    const int n0 = nbase + l15, n1 = nbase + 16 + l15;
    const int n0c = min(n0, N_NODES - 1), n1c = min(n1, N_NODES - 1);
    const _Float16* r0 = h2 + (size_t)n0c * 128;
    const _Float16* r1 = h2 + (size_t)n1c * 128;

    f4 accP[2][8], accQ[2][8];
#pragma unroll
    for (int t = 0; t < 2; t++)
#pragma unroll
        for (int nt = 0; nt < 8; nt++) {
            accP[t][nt] = (f4){0.f, 0.f, 0.f, 0.f};
            accQ[t][nt] = (f4){0.f, 0.f, 0.f, 0.f};
        }

#pragma unroll
    for (int ks = 0; ks < 4; ks++) {
        h8 a0 = ld_h8(r0 + ks * 32 + q * 8);
        h8 a1 = ld_h8(r1 + ks * 32 + q * 8);
#pragma unroll
        for (int nt = 0; nt < 8; nt++) {
            const int nrow = nt * 16 + l15;
            const int cP = ((ks << 2) | q) ^ (nrow & 31);
            h8 bP = ld_h8(Bsh + (((nrow << 5) | cP) << 3));
            accP[0][nt] = __builtin_amdgcn_mfma_f32_16x16x32_f16(a0, bP, accP[0][nt], 0, 0, 0);
            accP[1][nt] = __builtin_amdgcn_mfma_f32_16x16x32_f16(a1, bP, accP[1][nt], 0, 0, 0);
            const int cQ = (((ks + 4) << 2) | q) ^ (nrow & 31);
            h8 bQ = ld_h8(Bsh + (((nrow << 5) | cQ) << 3));
            accQ[0][nt] = __builtin_amdgcn_mfma_f32_16x16x32_f16(a0, bQ, accQ[0][nt], 0, 0, 0);
            accQ[1][nt] = __builtin_amdgcn_mfma_f32_16x16x32_f16(a1, bQ, accQ[1][nt], 0, 0, 0);
        }
    }

#pragma unroll
    for (int nt = 0; nt < 8; nt++) {
        const int col = nt * 16 + l15;
        const float bq = b1[col];
#pragma unroll
        for (int t = 0; t < 2; t++)
#pragma unroll
            for (int r = 0; r < 4; r++) {
                const int node = nbase + t * 16 + q * 4 + r;
                if (node < N_NODES) {
                    P[(size_t)node * 128 + col] = (_Float16)accP[t][nt][r];
                    Q[(size_t)node * 128 + col] = accQ[t][nt][r] + bq;
                }
            }
    }
}

// ---------------- elementwise edge predictor ----------------
// One edge per thread, dst-sorted slot order. out[e] = relu(P[src]+Q[dst])@W2+b2.
// No MFMA, no barriers (after the 1-KB W2 stage): pure gather + VALU.
// P[src] is the only random gather (256 B/edge); Q[dst] rows are shared by
// ~32 consecutive lanes (sorted) -> L1 broadcast.
__launch_bounds__(256, 4)
__global__ void pred_elem_kernel(const _Float16* __restrict__ P,
                                 const float* __restrict__ Q,
                                 const int2* __restrict__ pairs,
                                 const int* __restrict__ dsts,
                                 const float* __restrict__ W2,   // [128][2]
                                 const float* __restrict__ b2,
                                 float* __restrict__ out)
{
    __shared__ __align__(16) float w20sh[128];
    __shared__ __align__(16) float w21sh[128];

    const int tid = threadIdx.x;
    if (tid < 128) {
        w20sh[tid] = W2[tid * 2 + 0];
        w21sh[tid] = W2[tid * 2 + 1];
    }
    __syncthreads();

    const int slot = blockIdx.x * 256 + tid;   // grid covers E exactly
    const int2 pr = pairs[slot];
    const int d = dsts[slot];
    const _Float16* prow = P + (size_t)pr.y * 128;
    const float* qrow = Q + (size_t)d * 128;

    float o0 = 0.f, o1 = 0.f;
#pragma unroll
    for (int c = 0; c < 4; c++) {              // 32 elements per chunk
        h8 pv[4];
#pragma unroll
        for (int i = 0; i < 4; i++) pv[i] = ld_h8(prow + c * 32 + i * 8);
        f4 qv[8];
#pragma unroll
        for (int i = 0; i < 8; i++) qv[i] = *(const f4*)(qrow + c * 32 + i * 4);
#pragma unroll
        for (int i = 0; i < 8; i++) {
            const f4 w0 = *(const f4*)(w20sh + c * 32 + i * 4);   // uniform -> broadcast
            const f4 w1 = *(const f4*)(w21sh + c * 32 + i * 4);
#pragma unroll
            for (int j = 0; j < 4; j++) {
                const float pvf = (float)pv[i >> 1][(i & 1) * 4 + j];
                const float y = fmaxf(pvf + qv[i][j], 0.f);
                o0 += y * w0[j];
                o1 += y * w1[j];
            }
        }
    }

    out[(size_t)pr.x * 2 + 0] = o0 + b2[0];
    out[(size_t)pr.x * 2 + 1] = o1 + b2[1];
}

// ---------------- legacy predictor (fallback when ws too small) ----------------
__launch_bounds__(256)
__global__ void pred_kernel(const _Float16* __restrict__ h2,
                            const int* __restrict__ src,
                            const int* __restrict__ dst,
                            const _Float16* __restrict__ W1t,  // [128][256] unpadded
                            const float* __restrict__ b1,
                            const float* __restrict__ W2,      // [128][2] fp32
                            const float* __restrict__ b2,
                            float* __restrict__ out)
{
    __shared__ __align__(16) _Float16 Bsh[128 * 256];

    const int tid = threadIdx.x;
    {
        const uint4* s4 = (const uint4*)W1t;
        uint4* d4 = (uint4*)Bsh;
        for (int i = tid; i < 4096; i += 256) {
            int n = i >> 5, c = i & 31;
            d4[(n << 5) | (c ^ (n & 31))] = s4[i];
        }
    }
    __syncthreads();

    const int wave = tid >> 6, lane = tid & 63;
    const int q = lane >> 4, l15 = lane & 15;
    const int ebase = blockIdx.x * 128 + wave * 32;

    const int e0 = ebase + l15, e1 = ebase + 16 + l15;
    const _Float16* rs0 = h2 + (size_t)src[e0] * 128;
    const _Float16* rd0 = h2 + (size_t)dst[e0] * 128;
    const _Float16* rs1 = h2 + (size_t)src[e1] * 128;
    const _Float16* rd1 = h2 + (size_t)dst[e1] * 128;

    f4 acc[2][8];
#pragma unroll
    for (int t = 0; t < 2; t++)
#pragma unroll
        for (int nt = 0; nt < 8; nt++) acc[t][nt] = (f4){0.f, 0.f, 0.f, 0.f};

#pragma unroll
    for (int ks = 0; ks < 8; ks++) {
        h8 a0, a1;
        if (ks < 4) {
            a0 = ld_h8(rs0 + ks * 32 + q * 8);
            a1 = ld_h8(rs1 + ks * 32 + q * 8);
        } else {
            a0 = ld_h8(rd0 + (ks - 4) * 32 + q * 8);
            a1 = ld_h8(rd1 + (ks - 4) * 32 + q * 8);
        }
#pragma unroll
        for (int nt = 0; nt < 8; nt++) {
            const int nrow = nt * 16 + l15;
            const int chunk = ((ks << 2) | q) ^ (nrow & 31);
            h8 b = ld_h8(Bsh + (((nrow << 5) | chunk) << 3));
            acc[0][nt] = __builtin_amdgcn_mfma_f32_16x16x32_f16(a0, b, acc[0][nt], 0, 0, 0);
            acc[1][nt] = __builtin_amdgcn_mfma_f32_16x16x32_f16(a1, b, acc[1][nt], 0, 0, 0);
        }
    }

    float o[2][4][2];
#pragma unroll
    for (int t = 0; t < 2; t++)
#pragma unroll
        for (int r = 0; r < 4; r++) { o[t][r][0] = 0.f; o[t][r][1] = 0.f; }

#pragma unroll
    for (int nt = 0; nt < 8; nt++) {
        const int nrow = nt * 16 + l15;
        const float bv = b1[nrow];
        const float w20 = W2[nrow * 2 + 0];
        const float w21 = W2[nrow * 2 + 1];
#pragma unroll
        for (int t = 0; t < 2; t++)
#pragma unroll
            for (int r = 0; r < 4; r++) {
                float y = fmaxf(acc[t][nt][r] + bv, 0.f);
                o[t][r][0] += y * w20;
                o[t][r][1] += y * w21;
            }
    }

#pragma unroll
    for (int m = 1; m < 16; m <<= 1) {
#pragma unroll
        for (int t = 0; t < 2; t++)
#pragma unroll
            for (int r = 0; r < 4; r++) {
                o[t][r][0] += __shfl_xor(o[t][r][0], m, 64);
                o[t][r][1] += __shfl_xor(o[t][r][1], m, 64);
            }
    }

    if (l15 < 8) {
        const int r = l15 >> 1, c = l15 & 1;
        const float bb = c ? b2[1] : b2[0];
#pragma unroll
        for (int t = 0; t < 2; t++) {
            float v0 = (r == 0) ? o[t][0][0] : (r == 1) ? o[t][1][0] : (r == 2) ? o[t][2][0] : o[t][3][0];
            float v1 = (r == 0) ? o[t][0][1] : (r == 1) ? o[t][1][1] : (r == 2) ? o[t][2][1] : o[t][3][1];
            float v = (c ? v1 : v0) + bb;
            out[(size_t)(ebase + t * 16 + q * 4 + r) * 2 + c] = v;
        }
    }
}

// ---------------- launch ----------------

extern "C" void kernel_launch(void* const* d_in, const int* in_sizes, int n_in,
                              void* d_out, int out_size, void* d_ws, size_t ws_size,
                              hipStream_t stream)
{
    const float* nfeats = (const float*)d_in[0];
    const float* efeats = (const float*)d_in[1];
    const int*   src    = (const int*)d_in[2];
    const int*   dst    = (const int*)d_in[3];
    const float* Wm1 = (const float*)d_in[4],  *bm1 = (const float*)d_in[5];
    const float* Wa1 = (const float*)d_in[6],  *ba1 = (const float*)d_in[7];
    const float* Wm2 = (const float*)d_in[8],  *bm2 = (const float*)d_in[9];
    const float* Wa2 = (const float*)d_in[10], *ba2 = (const float*)d_in[11];
    const float* W1  = (const float*)d_in[12], *b1  = (const float*)d_in[13];
    const float* W2  = (const float*)d_in[14], *b2  = (const float*)d_in[15];
    float* out = (float*)d_out;

    char* ws = (char*)d_ws;
    float*     s     = (float*)(ws);                   // 25,600,000 B (sacc; later Q fp32 [N][128])
    int*       cnt   = (int*)(ws + 25600000);          //    200,000 B
    int*       tmp   = (int*)(ws + 25800000);          //    200,000 B
    int*       cursor= (int*)(ws + 26000000);          //    200,000 B
    int*       bsum  = (int*)(ws + 26200000);          //      1,024 B
    int*       bbase = (int*)(ws + 26201024);          //      1,024 B
    _Float16*  nf16  = (_Float16*)(ws + 26202048);     //  6,400,000 B
    int2*      pairs = (int2*)(ws + 32602048);         // 12,800,000 B (edge_id, src) per sorted slot
    int*       dsts  = (int*)(ws + 45402048);          //  6,400,000 B dst per sorted slot
    _Float16*  h1    = (_Float16*)(ws + 51802048);     // 12,800,000 B (h1; later P fp16 [N][128])
    _Float16*  Wm1t  = (_Float16*)(ws + 64602048);     //     24,576 B (msg image, K=96)
    _Float16*  Wa1t  = (_Float16*)(ws + 64626624);     //     51,200 B
    _Float16*  Wm2t  = (_Float16*)(ws + 64677824);     //     40,960 B (msg image, K=160)
    _Float16*  Wa2t  = (_Float16*)(ws + 64718784);     //     65,536 B
    _Float16*  W1t   = (_Float16*)(ws + 64784320);     //     65,536 B  -> 64,849,856

    // h2 placement: fresh region when ws allows (keeps pairs/dsts live for the
    // sorted predictor path); else alias nf16+pairs-head and use legacy pred.
    const bool big_ws = ws_size >= (size_t)77800000;
    _Float16* h2 = big_ws ? (_Float16*)(ws + 64849920)   // +12,800,000 -> end 77,649,920
                          : (_Float16*)(ws + 26202048);

    hipMemsetAsync(s, 0, 25600000, stream);
    hipMemsetAsync(cnt, 0, 200000, stream);

    prep_weights<<<480, 256, 0, stream>>>(Wm1, Wa1, Wm2, Wa2, W1, Wm1t, Wa1t, Wm2t, Wa2t, W1t);
    cvt_nfeats<<<12500, 256, 0, stream>>>(nfeats, nf16);

    // counting sort of edges by dst
    hist_kernel<<<6250, 256, 0, stream>>>(dst, cnt);
    scan1_kernel<<<196, 256, 0, stream>>>(cnt, tmp, bsum);
    scan2_kernel<<<1, 256, 0, stream>>>(bsum, bbase);
    scan3_kernel<<<196, 256, 0, stream>>>(cnt, tmp, bbase, cursor);
    scatter_kernel<<<6250, 256, 0, stream>>>(src, dst, cursor, pairs, dsts);

    // layer 1 (LDS 33792 B -> 4 blocks/CU)
    msg_kernel_sorted<64, 5><<<12500, 256, 0, stream>>>(nf16, efeats, pairs, dsts, Wm1t, bm1, s);
    apply_kernel<64, false, 200><<<391, 256, 0, stream>>>(nf16, s, cnt, Wa1t, ba1, h1);

    // layer 2 (LDS 40960 B = exactly 4 blocks/CU)
    hipMemsetAsync(s, 0, 25600000, stream);
    msg_kernel_sorted<128, 4><<<12500, 256, 0, stream>>>(h1, efeats, pairs, dsts, Wm2t, bm2, s);
    apply_kernel<128, true, 256><<<391, 256, 0, stream>>>(h1, s, cnt, Wa2t, ba2, h2);

    // predictor
    if (big_ws) {
        // P reuses h1's slot, Q reuses s (both dead after apply2)
        _Float16* P = h1;
        float*    Q = s;
        node_pq_kernel<<<391, 256, 0, stream>>>(h2, W1t, b1, P, Q);
        pred_elem_kernel<<<6250, 256, 0, stream>>>(P, Q, pairs, dsts, W2, b2, out);
    } else {
        pred_kernel<<<12500, 256, 0, stream>>>(h2, src, dst, W1t, b1, W2, b2, out);
    }
}